// Round 14
// baseline (3957.618 us; speedup 1.0000x reference)
//
#include <hip/hip_runtime.h>
#include <hip/hip_bf16.h>

#define NLAYERS 6
#define BB 8
#define TT 512
#define DMODEL 2048
#define DSTATE 128
#define DCONV 4
#define DINNER 4096
#define NTOK (BB*TT)              // 4096 tokens
#define NKSPLIT_XP 16

typedef __bf16 bf16x8 __attribute__((ext_vector_type(8)));
typedef float floatx4 __attribute__((ext_vector_type(4)));
typedef unsigned short ushort8v __attribute__((ext_vector_type(8)));
typedef unsigned short ushort4v __attribute__((ext_vector_type(4)));

__device__ __forceinline__ float bf2f(unsigned short u) {
    return __uint_as_float(((unsigned)u) << 16);
}
__device__ __forceinline__ unsigned short f2bf(float f) {
    unsigned u = __float_as_uint(f);
    unsigned r = u + 0x7FFFu + ((u >> 16) & 1u);   // round-nearest-even
    return (unsigned short)(r >> 16);
}
__device__ __forceinline__ float siluf(float x) { return x / (1.f + __expf(-x)); }
__device__ __forceinline__ float softplusf(float x) {
    return fmaxf(x, 0.f) + log1pf(__expf(-fabsf(x)));
}

__device__ __forceinline__ void gload16(const void* g, void* l) {
    __builtin_amdgcn_global_load_lds(
        (const __attribute__((address_space(1))) void*)g,
        (__attribute__((address_space(3))) void*)l, 16, 0, 0);
}

__device__ __forceinline__ int2 pack_fp8x8(const float* v, float scale) {
    int lo = __builtin_amdgcn_cvt_pk_fp8_f32(v[0] * scale, v[1] * scale, 0, false);
    lo = __builtin_amdgcn_cvt_pk_fp8_f32(v[2] * scale, v[3] * scale, lo, true);
    int hi = __builtin_amdgcn_cvt_pk_fp8_f32(v[4] * scale, v[5] * scale, 0, false);
    hi = __builtin_amdgcn_cvt_pk_fp8_f32(v[6] * scale, v[7] * scale, hi, true);
    int2 o = {lo, hi};
    return o;
}

#define BARR __builtin_amdgcn_s_barrier()
#define SCHB __builtin_amdgcn_sched_barrier(0)
#define PRIO1 __builtin_amdgcn_s_setprio(1)
#define PRIO0 __builtin_amdgcn_s_setprio(0)

// ---------------- fp32 -> fp8 e4m3 (scaled) conversion ----------------
__global__ __launch_bounds__(256) void cvt8_kernel(const float* __restrict__ s,
                                                   unsigned char* __restrict__ d,
                                                   float scale) {
    int i = (blockIdx.x * blockDim.x + threadIdx.x) * 8;
    float v[8];
    float4 v0 = *(const float4*)(s + i);
    float4 v1 = *(const float4*)(s + i + 4);
    v[0]=v0.x; v[1]=v0.y; v[2]=v0.z; v[3]=v0.w;
    v[4]=v1.x; v[5]=v1.y; v[6]=v1.z; v[7]=v1.w;
    *(int2*)(d + i) = pack_fp8x8(v, scale);
}

// ---------------- fused (p0+p1+h) + LayerNorm: fp32 in -> h fp32 + xn fp8(x4) ----------------
__global__ __launch_bounds__(256) void ln3_kernel(const float* __restrict__ p0,
                                                  const float* __restrict__ p1,
                                                  const float* __restrict__ hin,
                                                  const float* __restrict__ g,
                                                  const float* __restrict__ b,
                                                  int hasP,
                                                  float* __restrict__ hout,
                                                  unsigned char* __restrict__ out8) {
    const int row = blockIdx.x;
    const long rb = (long)row * DMODEL;
    const int base = threadIdx.x * 8;
    float vv[8];
    float4 v0 = *(const float4*)(hin + rb + base);
    float4 v1 = *(const float4*)(hin + rb + base + 4);
    vv[0]=v0.x; vv[1]=v0.y; vv[2]=v0.z; vv[3]=v0.w;
    vv[4]=v1.x; vv[5]=v1.y; vv[6]=v1.z; vv[7]=v1.w;
    if (hasP) {
        float4 a0 = *(const float4*)(p0 + rb + base);
        float4 a1 = *(const float4*)(p0 + rb + base + 4);
        float4 c0 = *(const float4*)(p1 + rb + base);
        float4 c1 = *(const float4*)(p1 + rb + base + 4);
        vv[0]+=a0.x+c0.x; vv[1]+=a0.y+c0.y; vv[2]+=a0.z+c0.z; vv[3]+=a0.w+c0.w;
        vv[4]+=a1.x+c1.x; vv[5]+=a1.y+c1.y; vv[6]+=a1.z+c1.z; vv[7]+=a1.w+c1.w;
        float4 w0 = {vv[0],vv[1],vv[2],vv[3]}, w1 = {vv[4],vv[5],vv[6],vv[7]};
        *(float4*)(hout + rb + base) = w0;
        *(float4*)(hout + rb + base + 4) = w1;
    }
    float s = 0.f, s2 = 0.f;
#pragma unroll
    for (int j = 0; j < 8; j++) { s += vv[j]; s2 += vv[j] * vv[j]; }
#pragma unroll
    for (int off = 32; off >= 1; off >>= 1) {
        s += __shfl_xor(s, off);
        s2 += __shfl_xor(s2, off);
    }
    __shared__ float red[8];
    int wave = threadIdx.x >> 6, lane = threadIdx.x & 63;
    if (lane == 0) { red[wave] = s; red[4 + wave] = s2; }
    __syncthreads();
    s = red[0] + red[1] + red[2] + red[3];
    s2 = red[4] + red[5] + red[6] + red[7];
    float mu = s * (1.f / DMODEL);
    float var = s2 * (1.f / DMODEL) - mu * mu;
    float rs = rsqrtf(var + 1e-5f);
    float nv[8];
#pragma unroll
    for (int j = 0; j < 8; j++)
        nv[j] = (vv[j] - mu) * rs * g[base + j] + b[base + j];
    *(int2*)&out8[rb + base] = pack_fp8x8(nv, 4.f);
}

// ---------------- final combine: out = p0 + p1 + h ----------------
__global__ __launch_bounds__(256) void combine3_kernel(const float* __restrict__ p0,
                                                       const float* __restrict__ p1,
                                                       const float* __restrict__ h,
                                                       float* __restrict__ out) {
    long i = (long)(blockIdx.x * blockDim.x + threadIdx.x) * 4;
    float4 a = *(const float4*)(p0 + i);
    float4 b = *(const float4*)(p1 + i);
    float4 c = *(const float4*)(h + i);
    float4 o = {a.x+b.x+c.x, a.y+b.y+c.y, a.z+b.z+c.z, a.w+b.w+c.w};
    *(float4*)(out + i) = o;
}

// ============ 256x256 fp8 GEMM, BK=64 bytes, 5-buffer LDS, prefetch depth 4 ============
// R12-verified dt8 structure generalized. 512 thr, 8 waves (wm=w>>2 M 128-band,
// wn=w&3 N 64-band), acc[8][4]. Per tile: vmcnt(12); barrier; STAGE(t+4, 4 gload16);
// 24 ds_read_b64; lgkm(12) -> 32 MFMA k0; lgkm(0) -> 32 MFMA k1.
// Swizzle: 2 rows/128B LDS row, stored slot = ((r&1)*4+chunk)^(ldsrow&7) (0-conflict).
// EPI: 0 = bf16 store *SC (W_in); 1 = softplus dmean (W_dt); 2 = bcp K-part *SC (W_xp);
//      3 = fp32 K-part *SC (W_out).
template <int EPI>
__global__ __launch_bounds__(512, 1) void gemm8(const unsigned char* __restrict__ A8,
                                                const unsigned char* __restrict__ B8,
                                                int KstrB, int KT, int ldc,
                                                unsigned short* __restrict__ obf,
                                                float* __restrict__ of0,
                                                float* __restrict__ of1,
                                                const float* __restrict__ bias,
                                                float* __restrict__ dmean,
                                                float SC) {
    __shared__ __align__(16) char lds[5 * 32768];
    const int tid = threadIdx.x;
    const int w = tid >> 6, lane = tid & 63;
    const int wm = w >> 2, wn = w & 3;

    const int xcd = blockIdx.x & 7;
    const int l = blockIdx.x >> 3;
    const int by = xcd * 2 + (l & 1);
    const int rest = l >> 1;
    int bx = 0, kpart = 0;
    if constexpr (EPI == 2) { kpart = rest; }
    else if constexpr (EPI == 3) { bx = rest & 7; kpart = rest >> 3; }
    else { bx = rest; }
    const long rowBase = (long)by * 256;
    const long colBase = (long)bx * 256;
    const long K0b = (long)kpart * KT * 64;

    // frag-read constants per kstep s: chunk = s*2+(lane>>5), inner 8B = ((lane>>4)&1)*8
    int cbs[2];
#pragma unroll
    for (int s = 0; s < 2; s++)
        cbs[s] = (((((lane & 1) << 2) | (s * 2 + (lane >> 5))) ^ ((lane >> 1) & 7)) * 16)
                 + ((lane >> 4) & 1) * 8;
    const char* rdA = lds + wm * 8192 + ((lane >> 1) & 7) * 128;
    const char* rdB = lds + 16384 + wn * 4096 + ((lane >> 1) & 7) * 128;

    // staging source (inverse-swizzled global addr, linear LDS dest)
    const int t8 = tid >> 3;
    const int ch3 = (tid & 7) ^ (t8 & 7);
    const int srow = 2 * t8 + (ch3 >> 2);
    const int coff = (ch3 & 3) * 16;
    const size_t Kb = (size_t)KstrB;
    const char* pA1 = (const char*)A8 + (rowBase + srow) * Kb + coff + K0b;
    const char* pA2 = (const char*)A8 + (rowBase + 128 + srow) * Kb + coff + K0b;
    const char* pB1 = (const char*)B8 + (colBase + srow) * Kb + coff + K0b;
    const char* pB2 = (const char*)B8 + (colBase + 128 + srow) * Kb + coff + K0b;
    const long wb = (long)w * 1024;

    floatx4 acc[8][4];
#pragma unroll
    for (int m = 0; m < 8; m++)
#pragma unroll
        for (int n = 0; n < 4; n++) acc[m][n] = floatx4{0.f, 0.f, 0.f, 0.f};

#define STG8(BUF, OFF) do { \
    gload16(pA1 + (OFF), lds + (BUF)*32768 + wb); \
    gload16(pA2 + (OFF), lds + (BUF)*32768 + 8192 + wb); \
    gload16(pB1 + (OFF), lds + (BUF)*32768 + 16384 + wb); \
    gload16(pB2 + (OFF), lds + (BUF)*32768 + 24576 + wb); } while(0)

    STG8(0, 0);
    STG8(1, (size_t)((1 < KT) ? 1 : KT - 1) * 64);
    STG8(2, (size_t)((2 < KT) ? 2 : KT - 1) * 64);
    STG8(3, (size_t)((3 < KT) ? 3 : KT - 1) * 64);

    for (int t = 0; t < KT; t++) {
        const long bo = (long)(t % 5) * 32768;
        const int bufS = (t + 4) % 5;
        const size_t off4 = (size_t)((t + 4 < KT) ? (t + 4) : (KT - 1)) * 64;
        asm volatile("s_waitcnt vmcnt(12)");
        BARR;
        STG8(bufS, off4);
        long b0[4], a0[8], b1[4], a1[8];
#pragma unroll
        for (int n = 0; n < 4; n++) b0[n] = *(const long*)(rdB + bo + n * 1024 + cbs[0]);
#pragma unroll
        for (int m = 0; m < 8; m++) a0[m] = *(const long*)(rdA + bo + m * 1024 + cbs[0]);
#pragma unroll
        for (int n = 0; n < 4; n++) b1[n] = *(const long*)(rdB + bo + n * 1024 + cbs[1]);
#pragma unroll
        for (int m = 0; m < 8; m++) a1[m] = *(const long*)(rdA + bo + m * 1024 + cbs[1]);
        asm volatile("s_waitcnt lgkmcnt(12)"); SCHB;
        PRIO1;
#pragma unroll
        for (int m = 0; m < 8; m++)
#pragma unroll
            for (int n = 0; n < 4; n++)
                acc[m][n] = __builtin_amdgcn_mfma_f32_16x16x32_fp8_fp8(b0[n], a0[m], acc[m][n], 0, 0, 0);
        PRIO0;
        asm volatile("s_waitcnt lgkmcnt(0)"); SCHB;
        PRIO1;
#pragma unroll
        for (int m = 0; m < 8; m++)
#pragma unroll
            for (int n = 0; n < 4; n++)
                acc[m][n] = __builtin_amdgcn_mfma_f32_16x16x32_fp8_fp8(b1[n], a1[m], acc[m][n], 0, 0, 0);
        PRIO0;
    }
#undef STG8

    // epilogue (M-row = lane&15, N-col = (lane>>4)*4 + reg)
    const int lrow = lane & 15, cg = (lane >> 4) * 4;
    if constexpr (EPI == 0) {
#pragma unroll
        for (int mi = 0; mi < 8; mi++)
#pragma unroll
            for (int n = 0; n < 4; n++) {
                long row = rowBase + wm * 128 + mi * 16 + lrow;
                long col = colBase + wn * 64 + n * 16 + cg;
                ushort4v o = {f2bf(acc[mi][n][0] * SC), f2bf(acc[mi][n][1] * SC),
                              f2bf(acc[mi][n][2] * SC), f2bf(acc[mi][n][3] * SC)};
                *(ushort4v*)&obf[row * ldc + col] = o;
            }
    } else if constexpr (EPI == 1) {
        float4 bi[4];
#pragma unroll
        for (int n = 0; n < 4; n++)
            bi[n] = *(const float4*)&bias[colBase + wn * 64 + n * 16 + cg];
#pragma unroll
        for (int mi = 0; mi < 8; mi++) {
            float s = 0.f;
#pragma unroll
            for (int n = 0; n < 4; n++) {
                s += softplusf(acc[mi][n][0] * SC + bi[n].x);
                s += softplusf(acc[mi][n][1] * SC + bi[n].y);
                s += softplusf(acc[mi][n][2] * SC + bi[n].z);
                s += softplusf(acc[mi][n][3] * SC + bi[n].w);
            }
            s += __shfl_xor(s, 16);
            s += __shfl_xor(s, 32);
            if ((lane >> 4) == 0)
                atomicAdd(&dmean[rowBase + wm * 128 + mi * 16 + lrow], s);
        }
    } else if constexpr (EPI == 2) {
        float* op = of0 + (long)kpart * NTOK * 256;
#pragma unroll
        for (int mi = 0; mi < 8; mi++)
#pragma unroll
            for (int n = 0; n < 4; n++) {
                long row = rowBase + wm * 128 + mi * 16 + lrow;
                long col = wn * 64 + n * 16 + cg;
                *(floatx4*)&op[row * 256 + col] = acc[mi][n] * SC;
            }
    } else {   // EPI == 3: fp32 K-split partial
        float* op = (kpart == 0) ? of0 : of1;
#pragma unroll
        for (int mi = 0; mi < 8; mi++)
#pragma unroll
            for (int n = 0; n < 4; n++) {
                long row = rowBase + wm * 128 + mi * 16 + lrow;
                long col = colBase + wn * 64 + n * 16 + cg;
                *(floatx4*)&op[row * ldc + col] = acc[mi][n] * SC;
            }
    }
}

// ---------------- causal depthwise conv1d + bias + silu (bf16 + scaled fp8 out) ----------------
__global__ __launch_bounds__(256) void conv_silu_kernel(const unsigned short* __restrict__ xr,
                                                        const float* __restrict__ w,
                                                        const float* __restrict__ cb,
                                                        unsigned short* __restrict__ xc,
                                                        unsigned char* __restrict__ xc8) {
    int idx = blockIdx.x * blockDim.x + threadIdx.x;   // NTOK * 512
    int d0 = (idx & 511) * 8;
    int bt = idx >> 9;
    int t = bt & (TT - 1);
    float acc[8];
#pragma unroll
    for (int j = 0; j < 8; j++) acc[j] = cb[d0 + j];
#pragma unroll
    for (int k = 0; k < DCONV; k++) {
        int ts = t - (DCONV - 1) + k;
        if (ts < 0) continue;
        ushort8v v = *(const ushort8v*)&xr[(long)(bt - (DCONV - 1) + k) * (2 * DINNER) + d0];
#pragma unroll
        for (int j = 0; j < 8; j++) acc[j] += bf2f(v[j]) * w[(d0 + j) * DCONV + k];
    }
    float sv[8];
    ushort8v ov;
#pragma unroll
    for (int j = 0; j < 8; j++) { sv[j] = siluf(acc[j]); ov[j] = f2bf(sv[j]); }
    *(ushort8v*)&xc[(long)bt * DINNER + d0] = ov;
    *(int2*)&xc8[(long)bt * DINNER + d0] = pack_fp8x8(sv, 4.f);
}

// ---------------- bc = sum of 16 K-split partials ----------------
__global__ __launch_bounds__(256) void bcsum_kernel(const float* __restrict__ bcp,
                                                    float* __restrict__ bc) {
    long i = (long)(blockIdx.x * blockDim.x + threadIdx.x) * 4;
    const long S = (long)NTOK * 256;
    float4 o = *(const float4*)(bcp + i);
#pragma unroll
    for (int p = 1; p < NKSPLIT_XP; p++) {
        float4 v = *(const float4*)(bcp + (long)p * S + i);
        o.x += v.x; o.y += v.y; o.z += v.z; o.w += v.w;
    }
    *(float4*)(bc + i) = o;
}

// ---------------- sequential selective-scan, 4-step batched reduction ----------------
__global__ void scan_kernel(const float* __restrict__ dmean, const float* __restrict__ bcmat,
                            const float* __restrict__ A_log, float* __restrict__ ys) {
    int b = blockIdx.x, lane = threadIdx.x;   // 64 lanes, 2 states each
    float A0 = -expf(A_log[lane]);
    float A1 = -expf(A_log[lane + 64]);
    float h0 = 0.f, h1 = 0.f;
    const float inv = 1.f / (float)DINNER;
    const float* rowp = bcmat + (long)b * TT * (2 * DSTATE);
    const float* dmp = dmean + b * TT;
    float B0 = rowp[lane], B1 = rowp[64 + lane];
    float C0 = rowp[128 + lane], C1 = rowp[192 + lane];
    float DM = dmp[0];
    for (int t0 = 0; t0 < TT; t0 += 4) {
        float vv0, vv1, vv2, vv3;
#define STEP(J, VV) do { \
        int t_ = t0 + (J); \
        float nB0 = 0.f, nB1 = 0.f, nC0 = 0.f, nC1 = 0.f, nDM = 0.f; \
        if (t_ + 1 < TT) { \
            const float* nx = rowp + (long)(t_ + 1) * 256; \
            nB0 = nx[lane]; nB1 = nx[64 + lane]; \
            nC0 = nx[128 + lane]; nC1 = nx[192 + lane]; \
            nDM = dmp[t_ + 1]; \
        } \
        float dm = DM * inv; \
        h0 = h0 * __expf(dm * A0) + B0; \
        h1 = h1 * __expf(dm * A1) + B1; \
        VV = h0 * C0 + h1 * C1; \
        B0 = nB0; B1 = nB1; C0 = nC0; C1 = nC1; DM = nDM; } while (0)
        STEP(0, vv0); STEP(1, vv1); STEP(2, vv2); STEP(3, vv3);
#undef STEP
#pragma unroll
        for (int off = 32; off >= 1; off >>= 1) {
            vv0 += __shfl_xor(vv0, off);
            vv1 += __shfl_xor(vv1, off);
            vv2 += __shfl_xor(vv2, off);
            vv3 += __shfl_xor(vv3, off);
        }
        if (lane == 0) {
            float4 o = {vv0, vv1, vv2, vv3};
            *(float4*)&ys[b * TT + t0] = o;
        }
    }
}

// ---------------- y = (ys + D_skip*xc) * silu(res) -> fp8 (x16) ----------------
__global__ __launch_bounds__(256) void ycomb_kernel(const float* __restrict__ ys,
                                                    const unsigned short* __restrict__ xc,
                                                    const unsigned short* __restrict__ xr,
                                                    const float* __restrict__ dskip,
                                                    unsigned char* __restrict__ yc8) {
    int idx = blockIdx.x * blockDim.x + threadIdx.x;
    int d0 = (idx & 511) * 8;
    int bt = idx >> 9;
    float y = ys[bt];
    ushort8v xcv = *(const ushort8v*)&xc[(long)bt * DINNER + d0];
    ushort8v rv = *(const ushort8v*)&xr[(long)bt * (2 * DINNER) + DINNER + d0];
    float val[8];
#pragma unroll
    for (int j = 0; j < 8; j++)
        val[j] = (y + dskip[d0 + j] * bf2f(xcv[j])) * siluf(bf2f(rv[j]));
    *(int2*)&yc8[(long)bt * DINNER + d0] = pack_fp8x8(val, 16.f);
}

extern "C" void kernel_launch(void* const* d_in, const int* in_sizes, int n_in,
                              void* d_out, int out_size, void* d_ws, size_t ws_size,
                              hipStream_t stream) {
    const float* x      = (const float*)d_in[0];
    const float* ln_g   = (const float*)d_in[1];
    const float* ln_b   = (const float*)d_in[2];
    const float* W_in   = (const float*)d_in[3];
    const float* conv_w = (const float*)d_in[4];
    const float* conv_b = (const float*)d_in[5];
    const float* W_xp   = (const float*)d_in[6];
    const float* W_dt   = (const float*)d_in[7];
    const float* b_dt   = (const float*)d_in[8];
    const float* A_log  = (const float*)d_in[9];
    const float* D_skip = (const float*)d_in[10];
    const float* W_out  = (const float*)d_in[11];
    float* out = (float*)d_out;

    // workspace carve
    char* ws = (char*)d_ws;
    const size_t nWin  = (size_t)2 * DINNER * DMODEL;
    const size_t nWdt  = (size_t)DINNER * DINNER;
    const size_t nWxp  = (size_t)2 * DSTATE * DINNER;
    const size_t nWout = (size_t)DMODEL * DINNER;

    unsigned char* wb_in8  = (unsigned char*)ws; ws += nWin;
    unsigned char* wb_dt8  = (unsigned char*)ws; ws += nWdt;
    unsigned char* wb_xp8  = (unsigned char*)ws; ws += nWxp;
    unsigned char* wb_out8 = (unsigned char*)ws; ws += nWout;
    unsigned char* xn8 = (unsigned char*)ws; ws += (size_t)NTOK * DMODEL;
    unsigned short* xr = (unsigned short*)ws; ws += (size_t)NTOK * 2 * DINNER * 2;
    unsigned short* xc = (unsigned short*)ws; ws += (size_t)NTOK * DINNER * 2;
    unsigned char*  xc8 = (unsigned char*)ws; ws += (size_t)NTOK * DINNER;
    unsigned char*  yc8 = (unsigned char*)ws; ws += (size_t)NTOK * DINNER;
    float* bc    = (float*)ws; ws += (size_t)NTOK * 2 * DSTATE * 4;
    float* bcp   = (float*)ws; ws += (size_t)NKSPLIT_XP * NTOK * 2 * DSTATE * 4;
    float* dmean = (float*)ws; ws += (size_t)NTOK * 4;
    float* ysb   = (float*)ws; ws += (size_t)NTOK * 4;
    float* h0    = (float*)ws; ws += (size_t)NTOK * DMODEL * 4;
    float* h1    = (float*)ws; ws += (size_t)NTOK * DMODEL * 4;
    float* p0    = (float*)ws; ws += (size_t)NTOK * DMODEL * 4;
    float* p1    = (float*)ws; ws += (size_t)NTOK * DMODEL * 4;

    const float* hprev = x;
    for (int lay = 0; lay < NLAYERS; lay++) {
        cvt8_kernel<<<(int)(nWin / 2048), 256, 0, stream>>>(W_in + (size_t)lay * nWin, wb_in8, 64.f);
        cvt8_kernel<<<(int)(nWdt / 2048), 256, 0, stream>>>(W_dt + (size_t)lay * nWdt, wb_dt8, 64.f);
        cvt8_kernel<<<(int)(nWxp / 2048), 256, 0, stream>>>(W_xp + (size_t)lay * nWxp, wb_xp8, 64.f);
        cvt8_kernel<<<(int)(nWout / 2048), 256, 0, stream>>>(W_out + (size_t)lay * nWout, wb_out8, 64.f);

        hipMemsetAsync(dmean, 0, (size_t)NTOK * 4, stream);

        // 1) fused residual-combine + LayerNorm -> h fp32 + xn fp8(x4)
        float* hcur = (lay & 1) ? h1 : h0;
        ln3_kernel<<<NTOK, 256, 0, stream>>>(p0, p1, hprev,
                                             ln_g + lay * DMODEL, ln_b + lay * DMODEL,
                                             lay > 0 ? 1 : 0, hcur, xn8);
        if (lay > 0) hprev = hcur;

        // 2) x_and_res = xn @ W_in^T  [4096 x 8192], K=2048B fp8: grid 16y x 32x = 512
        gemm8<0><<<512, 512, 0, stream>>>(xn8, wb_in8, DMODEL, 32, 2 * DINNER,
                                          xr, nullptr, nullptr, nullptr, nullptr, 1.f / 256.f);

        // 3) causal depthwise conv + silu (bf16 + fp8 outputs)
        conv_silu_kernel<<<NTOK * 512 / 256, 256, 0, stream>>>(
            xr, conv_w + (size_t)lay * DINNER * DCONV, conv_b + (size_t)lay * DINNER, xc, xc8);

        // 4a) W_dt fp8 GEMM [4096 x 4096], K=4096B: grid 16y x 16x = 256
        gemm8<1><<<256, 512, 0, stream>>>(xc8, wb_dt8, DINNER, 64, 0,
                                          nullptr, nullptr, nullptr,
                                          b_dt + (size_t)lay * DINNER, dmean, 1.f / 256.f);

        // 4b) W_xp fp8 GEMM [4096 x 256], K-split x16 (KT=4): grid 16y x 16k = 256
        gemm8<2><<<256, 512, 0, stream>>>(xc8, wb_xp8, DINNER, 4, 0,
                                          nullptr, bcp, nullptr, nullptr, nullptr, 1.f / 256.f);

        // 4c) bc = sum of partials
        bcsum_kernel<<<(NTOK * 256 / 4) / 256, 256, 0, stream>>>(bcp, bc);

        // 5) sequential scan -> ys
        scan_kernel<<<BB, 64, 0, stream>>>(dmean, bc, A_log + (size_t)lay * DSTATE, ysb);

        // 6) y = (ys + D_skip*xc) * silu(res) -> fp8(x16)
        ycomb_kernel<<<NTOK * 512 / 256, 256, 0, stream>>>(
            ysb, xc, xr, D_skip + (size_t)lay * DINNER, yc8);

        // 7) W_out partials [4096 x 2048], K-split x2 (KT=32): grid 16y x 8x x 2k = 256
        gemm8<3><<<256, 512, 0, stream>>>(yc8, wb_out8, DINNER, 32, DMODEL,
                                          nullptr, p0, p1, nullptr, nullptr, 1.f / 1024.f);
    }

    // final: out = p0 + p1 + h5
    combine3_kernel<<<(NTOK * DMODEL / 4) / 256, 256, 0, stream>>>(p0, p1, hprev, out);

    (void)in_sizes; (void)n_in; (void)out_size; (void)ws_size;
}

// Round 15
// 3805.087 us; speedup vs baseline: 1.0401x; 1.0401x over previous
//
#include <hip/hip_runtime.h>
#include <hip/hip_bf16.h>

#define NLAYERS 6
#define BB 8
#define TT 512
#define DMODEL 2048
#define DSTATE 128
#define DCONV 4
#define DINNER 4096
#define NTOK (BB*TT)              // 4096 tokens
#define NKSPLIT_XP 16

typedef __bf16 bf16x8 __attribute__((ext_vector_type(8)));
typedef float floatx4 __attribute__((ext_vector_type(4)));
typedef unsigned short ushort8v __attribute__((ext_vector_type(8)));
typedef unsigned short ushort4v __attribute__((ext_vector_type(4)));

__device__ __forceinline__ float bf2f(unsigned short u) {
    return __uint_as_float(((unsigned)u) << 16);
}
__device__ __forceinline__ unsigned short f2bf(float f) {
    unsigned u = __float_as_uint(f);
    unsigned r = u + 0x7FFFu + ((u >> 16) & 1u);   // round-nearest-even
    return (unsigned short)(r >> 16);
}
__device__ __forceinline__ float siluf(float x) { return x / (1.f + __expf(-x)); }
__device__ __forceinline__ float softplusf(float x) {
    return fmaxf(x, 0.f) + log1pf(__expf(-fabsf(x)));
}

__device__ __forceinline__ void gload16(const void* g, void* l) {
    __builtin_amdgcn_global_load_lds(
        (const __attribute__((address_space(1))) void*)g,
        (__attribute__((address_space(3))) void*)l, 16, 0, 0);
}

__device__ __forceinline__ int2 pack_fp8x8(const float* v, float scale) {
    int lo = __builtin_amdgcn_cvt_pk_fp8_f32(v[0] * scale, v[1] * scale, 0, false);
    lo = __builtin_amdgcn_cvt_pk_fp8_f32(v[2] * scale, v[3] * scale, lo, true);
    int hi = __builtin_amdgcn_cvt_pk_fp8_f32(v[4] * scale, v[5] * scale, 0, false);
    hi = __builtin_amdgcn_cvt_pk_fp8_f32(v[6] * scale, v[7] * scale, hi, true);
    int2 o = {lo, hi};
    return o;
}

#define BARR __builtin_amdgcn_s_barrier()
#define SCHB __builtin_amdgcn_sched_barrier(0)
#define PRIO1 __builtin_amdgcn_s_setprio(1)
#define PRIO0 __builtin_amdgcn_s_setprio(0)

// ---- fused all-weights fp32->fp8(x64) conversion + dmean zeroing (1 dispatch/layer) ----
// Region sizes are multiples of 2048 elements, so a 256-thr x 8-elem block never straddles.
__global__ __launch_bounds__(256) void cvtall_kernel(const float* __restrict__ Win,
                                                     const float* __restrict__ Wdt,
                                                     const float* __restrict__ Wxp,
                                                     const float* __restrict__ Wout,
                                                     unsigned char* __restrict__ dIn,
                                                     unsigned char* __restrict__ dDt,
                                                     unsigned char* __restrict__ dXp,
                                                     unsigned char* __restrict__ dOut,
                                                     float* __restrict__ dmean) {
    const long nWin  = (long)2 * DINNER * DMODEL;
    const long nWdt  = (long)DINNER * DINNER;
    const long nWxp  = (long)2 * DSTATE * DINNER;
    const long cum1 = nWin, cum2 = cum1 + nWdt, cum3 = cum2 + nWxp;
    long i = (long)blockIdx.x * 2048 + threadIdx.x * 8;
    const float* s; unsigned char* d; long off;
    if (i < cum1)      { s = Win;  d = dIn;  off = i; }
    else if (i < cum2) { s = Wdt;  d = dDt;  off = i - cum1; }
    else if (i < cum3) { s = Wxp;  d = dXp;  off = i - cum2; }
    else               { s = Wout; d = dOut; off = i - cum3; }
    float v[8];
    float4 v0 = *(const float4*)(s + off);
    float4 v1 = *(const float4*)(s + off + 4);
    v[0]=v0.x; v[1]=v0.y; v[2]=v0.z; v[3]=v0.w;
    v[4]=v1.x; v[5]=v1.y; v[6]=v1.z; v[7]=v1.w;
    *(int2*)(d + off) = pack_fp8x8(v, 64.f);
    if (blockIdx.x < 8) {
        float2 z = {0.f, 0.f};
        *(float2*)&dmean[(blockIdx.x * 256 + threadIdx.x) * 2] = z;
    }
}

// ---------------- fused (p0+p1+h) + LayerNorm: fp32 in -> h fp32 + xn fp8(x4) ----------------
__global__ __launch_bounds__(256) void ln3_kernel(const float* __restrict__ p0,
                                                  const float* __restrict__ p1,
                                                  const float* __restrict__ hin,
                                                  const float* __restrict__ g,
                                                  const float* __restrict__ b,
                                                  int hasP,
                                                  float* __restrict__ hout,
                                                  unsigned char* __restrict__ out8) {
    const int row = blockIdx.x;
    const long rb = (long)row * DMODEL;
    const int base = threadIdx.x * 8;
    float vv[8];
    float4 v0 = *(const float4*)(hin + rb + base);
    float4 v1 = *(const float4*)(hin + rb + base + 4);
    vv[0]=v0.x; vv[1]=v0.y; vv[2]=v0.z; vv[3]=v0.w;
    vv[4]=v1.x; vv[5]=v1.y; vv[6]=v1.z; vv[7]=v1.w;
    if (hasP) {
        float4 a0 = *(const float4*)(p0 + rb + base);
        float4 a1 = *(const float4*)(p0 + rb + base + 4);
        float4 c0 = *(const float4*)(p1 + rb + base);
        float4 c1 = *(const float4*)(p1 + rb + base + 4);
        vv[0]+=a0.x+c0.x; vv[1]+=a0.y+c0.y; vv[2]+=a0.z+c0.z; vv[3]+=a0.w+c0.w;
        vv[4]+=a1.x+c1.x; vv[5]+=a1.y+c1.y; vv[6]+=a1.z+c1.z; vv[7]+=a1.w+c1.w;
        float4 w0 = {vv[0],vv[1],vv[2],vv[3]}, w1 = {vv[4],vv[5],vv[6],vv[7]};
        *(float4*)(hout + rb + base) = w0;
        *(float4*)(hout + rb + base + 4) = w1;
    }
    float s = 0.f, s2 = 0.f;
#pragma unroll
    for (int j = 0; j < 8; j++) { s += vv[j]; s2 += vv[j] * vv[j]; }
#pragma unroll
    for (int off = 32; off >= 1; off >>= 1) {
        s += __shfl_xor(s, off);
        s2 += __shfl_xor(s2, off);
    }
    __shared__ float red[8];
    int wave = threadIdx.x >> 6, lane = threadIdx.x & 63;
    if (lane == 0) { red[wave] = s; red[4 + wave] = s2; }
    __syncthreads();
    s = red[0] + red[1] + red[2] + red[3];
    s2 = red[4] + red[5] + red[6] + red[7];
    float mu = s * (1.f / DMODEL);
    float var = s2 * (1.f / DMODEL) - mu * mu;
    float rs = rsqrtf(var + 1e-5f);
    float nv[8];
#pragma unroll
    for (int j = 0; j < 8; j++)
        nv[j] = (vv[j] - mu) * rs * g[base + j] + b[base + j];
    *(int2*)&out8[rb + base] = pack_fp8x8(nv, 4.f);
}

// ---------------- final combine: out = p0 + p1 + h ----------------
__global__ __launch_bounds__(256) void combine3_kernel(const float* __restrict__ p0,
                                                       const float* __restrict__ p1,
                                                       const float* __restrict__ h,
                                                       float* __restrict__ out) {
    long i = (long)(blockIdx.x * blockDim.x + threadIdx.x) * 4;
    float4 a = *(const float4*)(p0 + i);
    float4 b = *(const float4*)(p1 + i);
    float4 c = *(const float4*)(h + i);
    float4 o = {a.x+b.x+c.x, a.y+b.y+c.y, a.z+b.z+c.z, a.w+b.w+c.w};
    *(float4*)(out + i) = o;
}

// ============ 256x256 fp8 GEMM, BK=64 bytes, 5-buffer LDS, prefetch depth 4 ============
// (R12/R14-verified structure.) EPI: 0 = bf16 store *SC (W_in); 1 = softplus dmean (W_dt);
// 2 = bcp K-part *SC (W_xp); 3 = fp32 K-part *SC (W_out).
template <int EPI>
__global__ __launch_bounds__(512, 1) void gemm8(const unsigned char* __restrict__ A8,
                                                const unsigned char* __restrict__ B8,
                                                int KstrB, int KT, int ldc,
                                                unsigned short* __restrict__ obf,
                                                float* __restrict__ of0,
                                                float* __restrict__ of1,
                                                const float* __restrict__ bias,
                                                float* __restrict__ dmean,
                                                float SC) {
    __shared__ __align__(16) char lds[5 * 32768];
    const int tid = threadIdx.x;
    const int w = tid >> 6, lane = tid & 63;
    const int wm = w >> 2, wn = w & 3;

    const int xcd = blockIdx.x & 7;
    const int l = blockIdx.x >> 3;
    const int by = xcd * 2 + (l & 1);
    const int rest = l >> 1;
    int bx = 0, kpart = 0;
    if constexpr (EPI == 2) { kpart = rest; }
    else if constexpr (EPI == 3) { bx = rest & 7; kpart = rest >> 3; }
    else { bx = rest; }
    const long rowBase = (long)by * 256;
    const long colBase = (long)bx * 256;
    const long K0b = (long)kpart * KT * 64;

    // frag-read constants per kstep s: chunk = s*2+(lane>>5), inner 8B = ((lane>>4)&1)*8
    int cbs[2];
#pragma unroll
    for (int s = 0; s < 2; s++)
        cbs[s] = (((((lane & 1) << 2) | (s * 2 + (lane >> 5))) ^ ((lane >> 1) & 7)) * 16)
                 + ((lane >> 4) & 1) * 8;
    const char* rdA = lds + wm * 8192 + ((lane >> 1) & 7) * 128;
    const char* rdB = lds + 16384 + wn * 4096 + ((lane >> 1) & 7) * 128;

    // staging source (inverse-swizzled global addr, linear LDS dest)
    const int t8 = tid >> 3;
    const int ch3 = (tid & 7) ^ (t8 & 7);
    const int srow = 2 * t8 + (ch3 >> 2);
    const int coff = (ch3 & 3) * 16;
    const size_t Kb = (size_t)KstrB;
    const char* pA1 = (const char*)A8 + (rowBase + srow) * Kb + coff + K0b;
    const char* pA2 = (const char*)A8 + (rowBase + 128 + srow) * Kb + coff + K0b;
    const char* pB1 = (const char*)B8 + (colBase + srow) * Kb + coff + K0b;
    const char* pB2 = (const char*)B8 + (colBase + 128 + srow) * Kb + coff + K0b;
    const long wb = (long)w * 1024;

    floatx4 acc[8][4];
#pragma unroll
    for (int m = 0; m < 8; m++)
#pragma unroll
        for (int n = 0; n < 4; n++) acc[m][n] = floatx4{0.f, 0.f, 0.f, 0.f};

#define STG8(BUF, OFF) do { \
    gload16(pA1 + (OFF), lds + (BUF)*32768 + wb); \
    gload16(pA2 + (OFF), lds + (BUF)*32768 + 8192 + wb); \
    gload16(pB1 + (OFF), lds + (BUF)*32768 + 16384 + wb); \
    gload16(pB2 + (OFF), lds + (BUF)*32768 + 24576 + wb); } while(0)

    STG8(0, 0);
    STG8(1, (size_t)((1 < KT) ? 1 : KT - 1) * 64);
    STG8(2, (size_t)((2 < KT) ? 2 : KT - 1) * 64);
    STG8(3, (size_t)((3 < KT) ? 3 : KT - 1) * 64);

    for (int t = 0; t < KT; t++) {
        const long bo = (long)(t % 5) * 32768;
        const int bufS = (t + 4) % 5;
        const size_t off4 = (size_t)((t + 4 < KT) ? (t + 4) : (KT - 1)) * 64;
        asm volatile("s_waitcnt vmcnt(12)");
        BARR;
        STG8(bufS, off4);
        long b0[4], a0[8], b1[4], a1[8];
#pragma unroll
        for (int n = 0; n < 4; n++) b0[n] = *(const long*)(rdB + bo + n * 1024 + cbs[0]);
#pragma unroll
        for (int m = 0; m < 8; m++) a0[m] = *(const long*)(rdA + bo + m * 1024 + cbs[0]);
#pragma unroll
        for (int n = 0; n < 4; n++) b1[n] = *(const long*)(rdB + bo + n * 1024 + cbs[1]);
#pragma unroll
        for (int m = 0; m < 8; m++) a1[m] = *(const long*)(rdA + bo + m * 1024 + cbs[1]);
        asm volatile("s_waitcnt lgkmcnt(12)"); SCHB;
        PRIO1;
#pragma unroll
        for (int m = 0; m < 8; m++)
#pragma unroll
            for (int n = 0; n < 4; n++)
                acc[m][n] = __builtin_amdgcn_mfma_f32_16x16x32_fp8_fp8(b0[n], a0[m], acc[m][n], 0, 0, 0);
        PRIO0;
        asm volatile("s_waitcnt lgkmcnt(0)"); SCHB;
        PRIO1;
#pragma unroll
        for (int m = 0; m < 8; m++)
#pragma unroll
            for (int n = 0; n < 4; n++)
                acc[m][n] = __builtin_amdgcn_mfma_f32_16x16x32_fp8_fp8(b1[n], a1[m], acc[m][n], 0, 0, 0);
        PRIO0;
    }
#undef STG8

    // epilogue (M-row = lane&15, N-col = (lane>>4)*4 + reg)
    const int lrow = lane & 15, cg = (lane >> 4) * 4;
    if constexpr (EPI == 0) {
#pragma unroll
        for (int mi = 0; mi < 8; mi++)
#pragma unroll
            for (int n = 0; n < 4; n++) {
                long row = rowBase + wm * 128 + mi * 16 + lrow;
                long col = colBase + wn * 64 + n * 16 + cg;
                ushort4v o = {f2bf(acc[mi][n][0] * SC), f2bf(acc[mi][n][1] * SC),
                              f2bf(acc[mi][n][2] * SC), f2bf(acc[mi][n][3] * SC)};
                *(ushort4v*)&obf[row * ldc + col] = o;
            }
    } else if constexpr (EPI == 1) {
        float4 bi[4];
#pragma unroll
        for (int n = 0; n < 4; n++)
            bi[n] = *(const float4*)&bias[colBase + wn * 64 + n * 16 + cg];
#pragma unroll
        for (int mi = 0; mi < 8; mi++) {
            float s = 0.f;
#pragma unroll
            for (int n = 0; n < 4; n++) {
                s += softplusf(acc[mi][n][0] * SC + bi[n].x);
                s += softplusf(acc[mi][n][1] * SC + bi[n].y);
                s += softplusf(acc[mi][n][2] * SC + bi[n].z);
                s += softplusf(acc[mi][n][3] * SC + bi[n].w);
            }
            s += __shfl_xor(s, 16);
            s += __shfl_xor(s, 32);
            if ((lane >> 4) == 0)
                atomicAdd(&dmean[rowBase + wm * 128 + mi * 16 + lrow], s);
        }
    } else if constexpr (EPI == 2) {
        float* op = of0 + (long)kpart * NTOK * 256;
#pragma unroll
        for (int mi = 0; mi < 8; mi++)
#pragma unroll
            for (int n = 0; n < 4; n++) {
                long row = rowBase + wm * 128 + mi * 16 + lrow;
                long col = wn * 64 + n * 16 + cg;
                *(floatx4*)&op[row * 256 + col] = acc[mi][n] * SC;
            }
    } else {   // EPI == 3: fp32 K-split partial
        float* op = (kpart == 0) ? of0 : of1;
#pragma unroll
        for (int mi = 0; mi < 8; mi++)
#pragma unroll
            for (int n = 0; n < 4; n++) {
                long row = rowBase + wm * 128 + mi * 16 + lrow;
                long col = colBase + wn * 64 + n * 16 + cg;
                *(floatx4*)&op[row * ldc + col] = acc[mi][n] * SC;
            }
    }
}

// ---------------- causal depthwise conv1d + bias + silu (bf16 + scaled fp8 out) ----------------
__global__ __launch_bounds__(256) void conv_silu_kernel(const unsigned short* __restrict__ xr,
                                                        const float* __restrict__ w,
                                                        const float* __restrict__ cb,
                                                        unsigned short* __restrict__ xc,
                                                        unsigned char* __restrict__ xc8) {
    int idx = blockIdx.x * blockDim.x + threadIdx.x;   // NTOK * 512
    int d0 = (idx & 511) * 8;
    int bt = idx >> 9;
    int t = bt & (TT - 1);
    float acc[8];
#pragma unroll
    for (int j = 0; j < 8; j++) acc[j] = cb[d0 + j];
#pragma unroll
    for (int k = 0; k < DCONV; k++) {
        int ts = t - (DCONV - 1) + k;
        if (ts < 0) continue;
        ushort8v v = *(const ushort8v*)&xr[(long)(bt - (DCONV - 1) + k) * (2 * DINNER) + d0];
#pragma unroll
        for (int j = 0; j < 8; j++) acc[j] += bf2f(v[j]) * w[(d0 + j) * DCONV + k];
    }
    float sv[8];
    ushort8v ov;
#pragma unroll
    for (int j = 0; j < 8; j++) { sv[j] = siluf(acc[j]); ov[j] = f2bf(sv[j]); }
    *(ushort8v*)&xc[(long)bt * DINNER + d0] = ov;
    *(int2*)&xc8[(long)bt * DINNER + d0] = pack_fp8x8(sv, 4.f);
}

// ---------------- bc = sum of 16 K-split partials ----------------
__global__ __launch_bounds__(256) void bcsum_kernel(const float* __restrict__ bcp,
                                                    float* __restrict__ bc) {
    long i = (long)(blockIdx.x * blockDim.x + threadIdx.x) * 4;
    const long S = (long)NTOK * 256;
    float4 o = *(const float4*)(bcp + i);
#pragma unroll
    for (int p = 1; p < NKSPLIT_XP; p++) {
        float4 v = *(const float4*)(bcp + (long)p * S + i);
        o.x += v.x; o.y += v.y; o.z += v.z; o.w += v.w;
    }
    *(float4*)(bc + i) = o;
}

// -------- sequential selective-scan, double-buffered 4-step batches (deep prefetch) --------
// Batch for iteration i+1 is loaded during iteration i's compute (~8 steps ≈ 400+ cyc ahead),
// fully covering L2 latency; previously loads led use by only ~30 cyc (1 step).
__global__ void scan_kernel(const float* __restrict__ dmean, const float* __restrict__ bcmat,
                            const float* __restrict__ A_log, float* __restrict__ ys) {
    int b = blockIdx.x, lane = threadIdx.x;   // 64 lanes, 2 states each
    float A0 = -expf(A_log[lane]);
    float A1 = -expf(A_log[lane + 64]);
    float h0 = 0.f, h1 = 0.f;
    const float inv = 1.f / (float)DINNER;
    const float* rowp = bcmat + (long)b * TT * (2 * DSTATE);
    const float* dmp = dmean + b * TT;

    float cB0[4], cB1[4], cC0[4], cC1[4]; float4 cDM;
    float nB0[4], nB1[4], nC0[4], nC1[4]; float4 nDM;

#define LOADB(B0_, B1_, C0_, C1_, DM_, T0) do { \
    int tt_ = (T0); if (tt_ > TT - 4) tt_ = TT - 4; \
    _Pragma("unroll") for (int j_ = 0; j_ < 4; j_++) { \
        const float* rp_ = rowp + (long)(tt_ + j_) * 256; \
        B0_[j_] = rp_[lane]; B1_[j_] = rp_[64 + lane]; \
        C0_[j_] = rp_[128 + lane]; C1_[j_] = rp_[192 + lane]; } \
    DM_ = *(const float4*)&dmp[tt_]; } while (0)

#define COMPUTE4(B0_, B1_, C0_, C1_, DM_, T0) do { \
    float vv_[4]; \
    const float dms_[4] = {DM_.x, DM_.y, DM_.z, DM_.w}; \
    _Pragma("unroll") for (int j_ = 0; j_ < 4; j_++) { \
        float dm_ = dms_[j_] * inv; \
        h0 = h0 * __expf(dm_ * A0) + B0_[j_]; \
        h1 = h1 * __expf(dm_ * A1) + B1_[j_]; \
        vv_[j_] = h0 * C0_[j_] + h1 * C1_[j_]; } \
    _Pragma("unroll") for (int off_ = 32; off_ >= 1; off_ >>= 1) { \
        vv_[0] += __shfl_xor(vv_[0], off_); vv_[1] += __shfl_xor(vv_[1], off_); \
        vv_[2] += __shfl_xor(vv_[2], off_); vv_[3] += __shfl_xor(vv_[3], off_); } \
    if (lane == 0) { \
        float4 o_ = {vv_[0], vv_[1], vv_[2], vv_[3]}; \
        *(float4*)&ys[b * TT + (T0)] = o_; } } while (0)

    LOADB(cB0, cB1, cC0, cC1, cDM, 0);
    LOADB(nB0, nB1, nC0, nC1, nDM, 4);

    for (int t0 = 0; t0 < TT; t0 += 8) {
        COMPUTE4(cB0, cB1, cC0, cC1, cDM, t0);
        LOADB(cB0, cB1, cC0, cC1, cDM, t0 + 8);       // for iteration t0+8 (phase A)
        COMPUTE4(nB0, nB1, nC0, nC1, nDM, t0 + 4);
        LOADB(nB0, nB1, nC0, nC1, nDM, t0 + 12);      // for iteration t0+8 (phase B)
    }
#undef LOADB
#undef COMPUTE4
}

// ---------------- y = (ys + D_skip*xc) * silu(res) -> fp8 (x16) ----------------
__global__ __launch_bounds__(256) void ycomb_kernel(const float* __restrict__ ys,
                                                    const unsigned short* __restrict__ xc,
                                                    const unsigned short* __restrict__ xr,
                                                    const float* __restrict__ dskip,
                                                    unsigned char* __restrict__ yc8) {
    int idx = blockIdx.x * blockDim.x + threadIdx.x;
    int d0 = (idx & 511) * 8;
    int bt = idx >> 9;
    float y = ys[bt];
    ushort8v xcv = *(const ushort8v*)&xc[(long)bt * DINNER + d0];
    ushort8v rv = *(const ushort8v*)&xr[(long)bt * (2 * DINNER) + DINNER + d0];
    float val[8];
#pragma unroll
    for (int j = 0; j < 8; j++)
        val[j] = (y + dskip[d0 + j] * bf2f(xcv[j])) * siluf(bf2f(rv[j]));
    *(int2*)&yc8[(long)bt * DINNER + d0] = pack_fp8x8(val, 16.f);
}

extern "C" void kernel_launch(void* const* d_in, const int* in_sizes, int n_in,
                              void* d_out, int out_size, void* d_ws, size_t ws_size,
                              hipStream_t stream) {
    const float* x      = (const float*)d_in[0];
    const float* ln_g   = (const float*)d_in[1];
    const float* ln_b   = (const float*)d_in[2];
    const float* W_in   = (const float*)d_in[3];
    const float* conv_w = (const float*)d_in[4];
    const float* conv_b = (const float*)d_in[5];
    const float* W_xp   = (const float*)d_in[6];
    const float* W_dt   = (const float*)d_in[7];
    const float* b_dt   = (const float*)d_in[8];
    const float* A_log  = (const float*)d_in[9];
    const float* D_skip = (const float*)d_in[10];
    const float* W_out  = (const float*)d_in[11];
    float* out = (float*)d_out;

    // workspace carve
    char* ws = (char*)d_ws;
    const size_t nWin  = (size_t)2 * DINNER * DMODEL;
    const size_t nWdt  = (size_t)DINNER * DINNER;
    const size_t nWxp  = (size_t)2 * DSTATE * DINNER;
    const size_t nWout = (size_t)DMODEL * DINNER;
    const int nCvtBlocks = (int)((nWin + nWdt + nWxp + nWout) / 2048);   // 20992

    unsigned char* wb_in8  = (unsigned char*)ws; ws += nWin;
    unsigned char* wb_dt8  = (unsigned char*)ws; ws += nWdt;
    unsigned char* wb_xp8  = (unsigned char*)ws; ws += nWxp;
    unsigned char* wb_out8 = (unsigned char*)ws; ws += nWout;
    unsigned char* xn8 = (unsigned char*)ws; ws += (size_t)NTOK * DMODEL;
    unsigned short* xr = (unsigned short*)ws; ws += (size_t)NTOK * 2 * DINNER * 2;
    unsigned short* xc = (unsigned short*)ws; ws += (size_t)NTOK * DINNER * 2;
    unsigned char*  xc8 = (unsigned char*)ws; ws += (size_t)NTOK * DINNER;
    unsigned char*  yc8 = (unsigned char*)ws; ws += (size_t)NTOK * DINNER;
    float* bc    = (float*)ws; ws += (size_t)NTOK * 2 * DSTATE * 4;
    float* bcp   = (float*)ws; ws += (size_t)NKSPLIT_XP * NTOK * 2 * DSTATE * 4;
    float* dmean = (float*)ws; ws += (size_t)NTOK * 4;
    float* ysb   = (float*)ws; ws += (size_t)NTOK * 4;
    float* h0    = (float*)ws; ws += (size_t)NTOK * DMODEL * 4;
    float* h1    = (float*)ws; ws += (size_t)NTOK * DMODEL * 4;
    float* p0    = (float*)ws; ws += (size_t)NTOK * DMODEL * 4;
    float* p1    = (float*)ws; ws += (size_t)NTOK * DMODEL * 4;

    const float* hprev = x;
    for (int lay = 0; lay < NLAYERS; lay++) {
        // 0) all weight converts + dmean zeroing, one dispatch
        cvtall_kernel<<<nCvtBlocks, 256, 0, stream>>>(
            W_in + (size_t)lay * nWin, W_dt + (size_t)lay * nWdt,
            W_xp + (size_t)lay * nWxp, W_out + (size_t)lay * nWout,
            wb_in8, wb_dt8, wb_xp8, wb_out8, dmean);

        // 1) fused residual-combine + LayerNorm -> h fp32 + xn fp8(x4)
        float* hcur = (lay & 1) ? h1 : h0;
        ln3_kernel<<<NTOK, 256, 0, stream>>>(p0, p1, hprev,
                                             ln_g + lay * DMODEL, ln_b + lay * DMODEL,
                                             lay > 0 ? 1 : 0, hcur, xn8);
        if (lay > 0) hprev = hcur;

        // 2) x_and_res = xn @ W_in^T  [4096 x 8192], K=2048B fp8: grid 16y x 32x = 512
        gemm8<0><<<512, 512, 0, stream>>>(xn8, wb_in8, DMODEL, 32, 2 * DINNER,
                                          xr, nullptr, nullptr, nullptr, nullptr, 1.f / 256.f);

        // 3) causal depthwise conv + silu (bf16 + fp8 outputs)
        conv_silu_kernel<<<NTOK * 512 / 256, 256, 0, stream>>>(
            xr, conv_w + (size_t)lay * DINNER * DCONV, conv_b + (size_t)lay * DINNER, xc, xc8);

        // 4a) W_dt fp8 GEMM [4096 x 4096], K=4096B: grid 16y x 16x = 256
        gemm8<1><<<256, 512, 0, stream>>>(xc8, wb_dt8, DINNER, 64, 0,
                                          nullptr, nullptr, nullptr,
                                          b_dt + (size_t)lay * DINNER, dmean, 1.f / 256.f);

        // 4b) W_xp fp8 GEMM [4096 x 256], K-split x16 (KT=4): grid 16y x 16k = 256
        gemm8<2><<<256, 512, 0, stream>>>(xc8, wb_xp8, DINNER, 4, 0,
                                          nullptr, bcp, nullptr, nullptr, nullptr, 1.f / 256.f);

        // 4c) bc = sum of partials
        bcsum_kernel<<<(NTOK * 256 / 4) / 256, 256, 0, stream>>>(bcp, bc);

        // 5) sequential scan -> ys (deep-prefetch)
        scan_kernel<<<BB, 64, 0, stream>>>(dmean, bc, A_log + (size_t)lay * DSTATE, ysb);

        // 6) y = (ys + D_skip*xc) * silu(res) -> fp8(x16)
        ycomb_kernel<<<NTOK * 512 / 256, 256, 0, stream>>>(
            ysb, xc, xr, D_skip + (size_t)lay * DINNER, yc8);

        // 7) W_out partials [4096 x 2048], K-split x2 (KT=32): grid 16y x 8x x 2k = 256
        gemm8<3><<<256, 512, 0, stream>>>(yc8, wb_out8, DINNER, 32, DMODEL,
                                          nullptr, p0, p1, nullptr, nullptr, 1.f / 1024.f);
    }

    // final: out = p0 + p1 + h5
    combine3_kernel<<<(NTOK * DMODEL / 4) / 256, 256, 0, stream>>>(p0, p1, hprev, out);

    (void)in_sizes; (void)n_in; (void)out_size; (void)ws_size;
}

// Round 16
// 3112.041 us; speedup vs baseline: 1.2717x; 1.2227x over previous
//
#include <hip/hip_runtime.h>
#include <hip/hip_bf16.h>

#define NLAYERS 6
#define BB 8
#define TT 512
#define DMODEL 2048
#define DSTATE 128
#define DCONV 4
#define DINNER 4096
#define NTOK (BB*TT)              // 4096 tokens
#define NKSPLIT_XP 16
#define NCVT 20992                // (nWin+nWdt+nWxp+nWout)/2048

typedef __bf16 bf16x8 __attribute__((ext_vector_type(8)));
typedef float floatx4 __attribute__((ext_vector_type(4)));
typedef unsigned short ushort8v __attribute__((ext_vector_type(8)));
typedef unsigned short ushort4v __attribute__((ext_vector_type(4)));

__device__ __forceinline__ float bf2f(unsigned short u) {
    return __uint_as_float(((unsigned)u) << 16);
}
__device__ __forceinline__ unsigned short f2bf(float f) {
    unsigned u = __float_as_uint(f);
    unsigned r = u + 0x7FFFu + ((u >> 16) & 1u);   // round-nearest-even
    return (unsigned short)(r >> 16);
}
__device__ __forceinline__ float siluf(float x) { return x / (1.f + __expf(-x)); }
__device__ __forceinline__ float softplusf(float x) {
    return fmaxf(x, 0.f) + log1pf(__expf(-fabsf(x)));
}

__device__ __forceinline__ void gload16(const void* g, void* l) {
    __builtin_amdgcn_global_load_lds(
        (const __attribute__((address_space(1))) void*)g,
        (__attribute__((address_space(3))) void*)l, 16, 0, 0);
}

__device__ __forceinline__ int2 pack_fp8x8(const float* v, float scale) {
    int lo = __builtin_amdgcn_cvt_pk_fp8_f32(v[0] * scale, v[1] * scale, 0, false);
    lo = __builtin_amdgcn_cvt_pk_fp8_f32(v[2] * scale, v[3] * scale, lo, true);
    int hi = __builtin_amdgcn_cvt_pk_fp8_f32(v[4] * scale, v[5] * scale, 0, false);
    hi = __builtin_amdgcn_cvt_pk_fp8_f32(v[6] * scale, v[7] * scale, hi, true);
    int2 o = {lo, hi};
    return o;
}

#define BARR __builtin_amdgcn_s_barrier()
#define SCHB __builtin_amdgcn_sched_barrier(0)
#define PRIO1 __builtin_amdgcn_s_setprio(1)
#define PRIO0 __builtin_amdgcn_s_setprio(0)

// ======= merged [LayerNorm(+residual) -> xn fp8] + [all-weight fp32->fp8 cvt + dmean zero] =======
// Blocks 0..NTOK-1: ln3 path (row = blockIdx). Blocks NTOK.. : weight conversion.
__global__ __launch_bounds__(256) void cvtln_kernel(const float* __restrict__ Win,
                                                    const float* __restrict__ Wdt,
                                                    const float* __restrict__ Wxp,
                                                    const float* __restrict__ Wout,
                                                    unsigned char* __restrict__ dIn,
                                                    unsigned char* __restrict__ dDt,
                                                    unsigned char* __restrict__ dXp,
                                                    unsigned char* __restrict__ dOut,
                                                    float* __restrict__ dmean,
                                                    const float* __restrict__ p0,
                                                    const float* __restrict__ p1,
                                                    const float* __restrict__ hin,
                                                    const float* __restrict__ g,
                                                    const float* __restrict__ b,
                                                    int hasP,
                                                    float* __restrict__ hout,
                                                    unsigned char* __restrict__ out8) {
    if (blockIdx.x < NTOK) {
        // ---- LayerNorm path ----
        const int row = blockIdx.x;
        const long rb = (long)row * DMODEL;
        const int base = threadIdx.x * 8;
        float vv[8];
        float4 v0 = *(const float4*)(hin + rb + base);
        float4 v1 = *(const float4*)(hin + rb + base + 4);
        vv[0]=v0.x; vv[1]=v0.y; vv[2]=v0.z; vv[3]=v0.w;
        vv[4]=v1.x; vv[5]=v1.y; vv[6]=v1.z; vv[7]=v1.w;
        if (hasP) {
            float4 a0 = *(const float4*)(p0 + rb + base);
            float4 a1 = *(const float4*)(p0 + rb + base + 4);
            float4 c0 = *(const float4*)(p1 + rb + base);
            float4 c1 = *(const float4*)(p1 + rb + base + 4);
            vv[0]+=a0.x+c0.x; vv[1]+=a0.y+c0.y; vv[2]+=a0.z+c0.z; vv[3]+=a0.w+c0.w;
            vv[4]+=a1.x+c1.x; vv[5]+=a1.y+c1.y; vv[6]+=a1.z+c1.z; vv[7]+=a1.w+c1.w;
            float4 w0 = {vv[0],vv[1],vv[2],vv[3]}, w1 = {vv[4],vv[5],vv[6],vv[7]};
            *(float4*)(hout + rb + base) = w0;
            *(float4*)(hout + rb + base + 4) = w1;
        }
        float s = 0.f, s2 = 0.f;
#pragma unroll
        for (int j = 0; j < 8; j++) { s += vv[j]; s2 += vv[j] * vv[j]; }
#pragma unroll
        for (int off = 32; off >= 1; off >>= 1) {
            s += __shfl_xor(s, off);
            s2 += __shfl_xor(s2, off);
        }
        __shared__ float red[8];
        int wave = threadIdx.x >> 6, lane = threadIdx.x & 63;
        if (lane == 0) { red[wave] = s; red[4 + wave] = s2; }
        __syncthreads();
        s = red[0] + red[1] + red[2] + red[3];
        s2 = red[4] + red[5] + red[6] + red[7];
        float mu = s * (1.f / DMODEL);
        float var = s2 * (1.f / DMODEL) - mu * mu;
        float rs = rsqrtf(var + 1e-5f);
        float nv[8];
#pragma unroll
        for (int j = 0; j < 8; j++)
            nv[j] = (vv[j] - mu) * rs * g[base + j] + b[base + j];
        *(int2*)&out8[rb + base] = pack_fp8x8(nv, 4.f);
    } else {
        // ---- weight conversion path ----
        const long nWin  = (long)2 * DINNER * DMODEL;
        const long nWdt  = (long)DINNER * DINNER;
        const long nWxp  = (long)2 * DSTATE * DINNER;
        const long cum1 = nWin, cum2 = cum1 + nWdt, cum3 = cum2 + nWxp;
        const int cb = blockIdx.x - NTOK;
        long i = (long)cb * 2048 + threadIdx.x * 8;
        const float* s; unsigned char* d; long off;
        if (i < cum1)      { s = Win;  d = dIn;  off = i; }
        else if (i < cum2) { s = Wdt;  d = dDt;  off = i - cum1; }
        else if (i < cum3) { s = Wxp;  d = dXp;  off = i - cum2; }
        else               { s = Wout; d = dOut; off = i - cum3; }
        float v[8];
        float4 v0 = *(const float4*)(s + off);
        float4 v1 = *(const float4*)(s + off + 4);
        v[0]=v0.x; v[1]=v0.y; v[2]=v0.z; v[3]=v0.w;
        v[4]=v1.x; v[5]=v1.y; v[6]=v1.z; v[7]=v1.w;
        *(int2*)(d + off) = pack_fp8x8(v, 64.f);
        if (cb < 8) {
            float2 z = {0.f, 0.f};
            *(float2*)&dmean[(cb * 256 + threadIdx.x) * 2] = z;
        }
    }
}

// ---------------- final combine: out = p0 + p1 + h ----------------
__global__ __launch_bounds__(256) void combine3_kernel(const float* __restrict__ p0,
                                                       const float* __restrict__ p1,
                                                       const float* __restrict__ h,
                                                       float* __restrict__ out) {
    long i = (long)(blockIdx.x * blockDim.x + threadIdx.x) * 4;
    float4 a = *(const float4*)(p0 + i);
    float4 b = *(const float4*)(p1 + i);
    float4 c = *(const float4*)(h + i);
    float4 o = {a.x+b.x+c.x, a.y+b.y+c.y, a.z+b.z+c.z, a.w+b.w+c.w};
    *(float4*)(out + i) = o;
}

// ============ 256x256 fp8 GEMM, BK=64 bytes, 5-buffer LDS, prefetch depth 4 ============
// (R12/R14-verified structure.) EPI: 0 = bf16 store *SC (W_in);
// 3 = fp32 K-part *SC (W_out); 4 = merged dt+xp (blocks <256: dt full-K softplus->dmean;
// blocks >=256: xp K-split x16 -> bcp partials, B = Bx8).
template <int EPI>
__global__ __launch_bounds__(512, 1) void gemm8(const unsigned char* __restrict__ A8,
                                                const unsigned char* __restrict__ B8,
                                                const unsigned char* __restrict__ Bx8,
                                                int KstrB, int KT, int ldc,
                                                unsigned short* __restrict__ obf,
                                                float* __restrict__ of0,
                                                float* __restrict__ of1,
                                                const float* __restrict__ bias,
                                                float* __restrict__ dmean,
                                                float SC) {
    __shared__ __align__(16) char lds[5 * 32768];
    const int tid = threadIdx.x;
    const int w = tid >> 6, lane = tid & 63;
    const int wm = w >> 2, wn = w & 3;

    int by, bx = 0, kpart = 0, KTloc = KT;
    bool isXp = false;
    const unsigned char* Bsel = B8;
    if constexpr (EPI == 4) {
        isXp = blockIdx.x >= 256;
        const int b2 = isXp ? (blockIdx.x - 256) : blockIdx.x;
        const int xcd = b2 & 7;
        const int l = b2 >> 3;
        by = xcd * 2 + (l & 1);
        const int rest = l >> 1;
        if (isXp) { kpart = rest; KTloc = 4; Bsel = Bx8; }
        else { bx = rest; KTloc = 64; }
    } else {
        const int xcd = blockIdx.x & 7;
        const int l = blockIdx.x >> 3;
        by = xcd * 2 + (l & 1);
        const int rest = l >> 1;
        if constexpr (EPI == 3) { bx = rest & 7; kpart = rest >> 3; }
        else { bx = rest; }
    }
    const long rowBase = (long)by * 256;
    const long colBase = (long)bx * 256;
    const long K0b = (long)kpart * KTloc * 64;

    // frag-read constants per kstep s: chunk = s*2+(lane>>5), inner 8B = ((lane>>4)&1)*8
    int cbs[2];
#pragma unroll
    for (int s = 0; s < 2; s++)
        cbs[s] = (((((lane & 1) << 2) | (s * 2 + (lane >> 5))) ^ ((lane >> 1) & 7)) * 16)
                 + ((lane >> 4) & 1) * 8;
    const char* rdA = lds + wm * 8192 + ((lane >> 1) & 7) * 128;
    const char* rdB = lds + 16384 + wn * 4096 + ((lane >> 1) & 7) * 128;

    // staging source (inverse-swizzled global addr, linear LDS dest)
    const int t8 = tid >> 3;
    const int ch3 = (tid & 7) ^ (t8 & 7);
    const int srow = 2 * t8 + (ch3 >> 2);
    const int coff = (ch3 & 3) * 16;
    const size_t Kb = (size_t)KstrB;
    const char* pA1 = (const char*)A8 + (rowBase + srow) * Kb + coff + K0b;
    const char* pA2 = (const char*)A8 + (rowBase + 128 + srow) * Kb + coff + K0b;
    const char* pB1 = (const char*)Bsel + (colBase + srow) * Kb + coff + K0b;
    const char* pB2 = (const char*)Bsel + (colBase + 128 + srow) * Kb + coff + K0b;
    const long wb = (long)w * 1024;

    floatx4 acc[8][4];
#pragma unroll
    for (int m = 0; m < 8; m++)
#pragma unroll
        for (int n = 0; n < 4; n++) acc[m][n] = floatx4{0.f, 0.f, 0.f, 0.f};

#define STG8(BUF, OFF) do { \
    gload16(pA1 + (OFF), lds + (BUF)*32768 + wb); \
    gload16(pA2 + (OFF), lds + (BUF)*32768 + 8192 + wb); \
    gload16(pB1 + (OFF), lds + (BUF)*32768 + 16384 + wb); \
    gload16(pB2 + (OFF), lds + (BUF)*32768 + 24576 + wb); } while(0)

    STG8(0, 0);
    STG8(1, (size_t)((1 < KTloc) ? 1 : KTloc - 1) * 64);
    STG8(2, (size_t)((2 < KTloc) ? 2 : KTloc - 1) * 64);
    STG8(3, (size_t)((3 < KTloc) ? 3 : KTloc - 1) * 64);

    for (int t = 0; t < KTloc; t++) {
        const long bo = (long)(t % 5) * 32768;
        const int bufS = (t + 4) % 5;
        const size_t off4 = (size_t)((t + 4 < KTloc) ? (t + 4) : (KTloc - 1)) * 64;
        asm volatile("s_waitcnt vmcnt(12)");
        BARR;
        STG8(bufS, off4);
        long b0[4], a0[8], b1[4], a1[8];
#pragma unroll
        for (int n = 0; n < 4; n++) b0[n] = *(const long*)(rdB + bo + n * 1024 + cbs[0]);
#pragma unroll
        for (int m = 0; m < 8; m++) a0[m] = *(const long*)(rdA + bo + m * 1024 + cbs[0]);
#pragma unroll
        for (int n = 0; n < 4; n++) b1[n] = *(const long*)(rdB + bo + n * 1024 + cbs[1]);
#pragma unroll
        for (int m = 0; m < 8; m++) a1[m] = *(const long*)(rdA + bo + m * 1024 + cbs[1]);
        asm volatile("s_waitcnt lgkmcnt(12)"); SCHB;
        PRIO1;
#pragma unroll
        for (int m = 0; m < 8; m++)
#pragma unroll
            for (int n = 0; n < 4; n++)
                acc[m][n] = __builtin_amdgcn_mfma_f32_16x16x32_fp8_fp8(b0[n], a0[m], acc[m][n], 0, 0, 0);
        PRIO0;
        asm volatile("s_waitcnt lgkmcnt(0)"); SCHB;
        PRIO1;
#pragma unroll
        for (int m = 0; m < 8; m++)
#pragma unroll
            for (int n = 0; n < 4; n++)
                acc[m][n] = __builtin_amdgcn_mfma_f32_16x16x32_fp8_fp8(b1[n], a1[m], acc[m][n], 0, 0, 0);
        PRIO0;
    }
#undef STG8

    // epilogue (M-row = lane&15, N-col = (lane>>4)*4 + reg)
    const int lrow = lane & 15, cg = (lane >> 4) * 4;
    if constexpr (EPI == 0) {
#pragma unroll
        for (int mi = 0; mi < 8; mi++)
#pragma unroll
            for (int n = 0; n < 4; n++) {
                long row = rowBase + wm * 128 + mi * 16 + lrow;
                long col = colBase + wn * 64 + n * 16 + cg;
                ushort4v o = {f2bf(acc[mi][n][0] * SC), f2bf(acc[mi][n][1] * SC),
                              f2bf(acc[mi][n][2] * SC), f2bf(acc[mi][n][3] * SC)};
                *(ushort4v*)&obf[row * ldc + col] = o;
            }
    } else if constexpr (EPI == 3) {
        float* op = (kpart == 0) ? of0 : of1;
#pragma unroll
        for (int mi = 0; mi < 8; mi++)
#pragma unroll
            for (int n = 0; n < 4; n++) {
                long row = rowBase + wm * 128 + mi * 16 + lrow;
                long col = colBase + wn * 64 + n * 16 + cg;
                *(floatx4*)&op[row * ldc + col] = acc[mi][n] * SC;
            }
    } else {   // EPI == 4: merged dt + xp
        if (!isXp) {
            float4 bi[4];
#pragma unroll
            for (int n = 0; n < 4; n++)
                bi[n] = *(const float4*)&bias[colBase + wn * 64 + n * 16 + cg];
#pragma unroll
            for (int mi = 0; mi < 8; mi++) {
                float s = 0.f;
#pragma unroll
                for (int n = 0; n < 4; n++) {
                    s += softplusf(acc[mi][n][0] * SC + bi[n].x);
                    s += softplusf(acc[mi][n][1] * SC + bi[n].y);
                    s += softplusf(acc[mi][n][2] * SC + bi[n].z);
                    s += softplusf(acc[mi][n][3] * SC + bi[n].w);
                }
                s += __shfl_xor(s, 16);
                s += __shfl_xor(s, 32);
                if ((lane >> 4) == 0)
                    atomicAdd(&dmean[rowBase + wm * 128 + mi * 16 + lrow], s);
            }
        } else {
            float* op = of0 + (long)kpart * NTOK * 256;
#pragma unroll
            for (int mi = 0; mi < 8; mi++)
#pragma unroll
                for (int n = 0; n < 4; n++) {
                    long row = rowBase + wm * 128 + mi * 16 + lrow;
                    long col = wn * 64 + n * 16 + cg;
                    *(floatx4*)&op[row * 256 + col] = acc[mi][n] * SC;
                }
        }
    }
}

// -------- causal depthwise conv1d + bias + silu, 4 tokens/thread (7 row-reads vs 16) --------
__global__ __launch_bounds__(256) void conv_silu4_kernel(const unsigned short* __restrict__ xr,
                                                         const float* __restrict__ w,
                                                         const float* __restrict__ cb,
                                                         unsigned short* __restrict__ xc,
                                                         unsigned char* __restrict__ xc8) {
    int idx = blockIdx.x * 256 + threadIdx.x;   // (NTOK/4) * 512 threads
    int d0 = (idx & 511) * 8;
    int g = idx >> 9;
    int bt0 = g * 4;
    int t0 = bt0 & (TT - 1);
    float rows[7][8];
#pragma unroll
    for (int j = 0; j < 7; j++) {
        if (t0 - 3 + j < 0) {
#pragma unroll
            for (int e = 0; e < 8; e++) rows[j][e] = 0.f;
        } else {
            ushort8v v = *(const ushort8v*)&xr[(long)(bt0 - 3 + j) * (2 * DINNER) + d0];
#pragma unroll
            for (int e = 0; e < 8; e++) rows[j][e] = bf2f(v[e]);
        }
    }
    float4 wv[8];
#pragma unroll
    for (int e = 0; e < 8; e++) wv[e] = *(const float4*)&w[(d0 + e) * DCONV];
    float cbv[8];
#pragma unroll
    for (int e = 0; e < 8; e++) cbv[e] = cb[d0 + e];
#pragma unroll
    for (int tj = 0; tj < 4; tj++) {
        float sv[8];
        ushort8v ov;
#pragma unroll
        for (int e = 0; e < 8; e++) {
            float a = cbv[e];
            a += rows[tj][e] * wv[e].x;
            a += rows[tj + 1][e] * wv[e].y;
            a += rows[tj + 2][e] * wv[e].z;
            a += rows[tj + 3][e] * wv[e].w;
            sv[e] = siluf(a);
            ov[e] = f2bf(sv[e]);
        }
        *(ushort8v*)&xc[(long)(bt0 + tj) * DINNER + d0] = ov;
        *(int2*)&xc8[(long)(bt0 + tj) * DINNER + d0] = pack_fp8x8(sv, 4.f);
    }
}

// ---------------- bc = sum of 16 K-split partials ----------------
__global__ __launch_bounds__(256) void bcsum_kernel(const float* __restrict__ bcp,
                                                    float* __restrict__ bc) {
    long i = (long)(blockIdx.x * blockDim.x + threadIdx.x) * 4;
    const long S = (long)NTOK * 256;
    float4 o = *(const float4*)(bcp + i);
#pragma unroll
    for (int p = 1; p < NKSPLIT_XP; p++) {
        float4 v = *(const float4*)(bcp + (long)p * S + i);
        o.x += v.x; o.y += v.y; o.z += v.z; o.w += v.w;
    }
    *(float4*)(bc + i) = o;
}

// -------- sequential selective-scan, double-buffered 4-step batches (deep prefetch) --------
__global__ void scan_kernel(const float* __restrict__ dmean, const float* __restrict__ bcmat,
                            const float* __restrict__ A_log, float* __restrict__ ys) {
    int b = blockIdx.x, lane = threadIdx.x;   // 64 lanes, 2 states each
    float A0 = -expf(A_log[lane]);
    float A1 = -expf(A_log[lane + 64]);
    float h0 = 0.f, h1 = 0.f;
    const float inv = 1.f / (float)DINNER;
    const float* rowp = bcmat + (long)b * TT * (2 * DSTATE);
    const float* dmp = dmean + b * TT;

    float cB0[4], cB1[4], cC0[4], cC1[4]; float4 cDM;
    float nB0[4], nB1[4], nC0[4], nC1[4]; float4 nDM;

#define LOADB(B0_, B1_, C0_, C1_, DM_, T0) do { \
    int tt_ = (T0); if (tt_ > TT - 4) tt_ = TT - 4; \
    _Pragma("unroll") for (int j_ = 0; j_ < 4; j_++) { \
        const float* rp_ = rowp + (long)(tt_ + j_) * 256; \
        B0_[j_] = rp_[lane]; B1_[j_] = rp_[64 + lane]; \
        C0_[j_] = rp_[128 + lane]; C1_[j_] = rp_[192 + lane]; } \
    DM_ = *(const float4*)&dmp[tt_]; } while (0)

#define COMPUTE4(B0_, B1_, C0_, C1_, DM_, T0) do { \
    float vv_[4]; \
    const float dms_[4] = {DM_.x, DM_.y, DM_.z, DM_.w}; \
    _Pragma("unroll") for (int j_ = 0; j_ < 4; j_++) { \
        float dm_ = dms_[j_] * inv; \
        h0 = h0 * __expf(dm_ * A0) + B0_[j_]; \
        h1 = h1 * __expf(dm_ * A1) + B1_[j_]; \
        vv_[j_] = h0 * C0_[j_] + h1 * C1_[j_]; } \
    _Pragma("unroll") for (int off_ = 32; off_ >= 1; off_ >>= 1) { \
        vv_[0] += __shfl_xor(vv_[0], off_); vv_[1] += __shfl_xor(vv_[1], off_); \
        vv_[2] += __shfl_xor(vv_[2], off_); vv_[3] += __shfl_xor(vv_[3], off_); } \
    if (lane == 0) { \
        float4 o_ = {vv_[0], vv_[1], vv_[2], vv_[3]}; \
        *(float4*)&ys[b * TT + (T0)] = o_; } } while (0)

    LOADB(cB0, cB1, cC0, cC1, cDM, 0);
    LOADB(nB0, nB1, nC0, nC1, nDM, 4);

    for (int t0 = 0; t0 < TT; t0 += 8) {
        COMPUTE4(cB0, cB1, cC0, cC1, cDM, t0);
        LOADB(cB0, cB1, cC0, cC1, cDM, t0 + 8);
        COMPUTE4(nB0, nB1, nC0, nC1, nDM, t0 + 4);
        LOADB(nB0, nB1, nC0, nC1, nDM, t0 + 12);
    }
#undef LOADB
#undef COMPUTE4
}

// ---------------- y = (ys + D_skip*xc) * silu(res) -> fp8 (x16) ----------------
__global__ __launch_bounds__(256) void ycomb_kernel(const float* __restrict__ ys,
                                                    const unsigned short* __restrict__ xc,
                                                    const unsigned short* __restrict__ xr,
                                                    const float* __restrict__ dskip,
                                                    unsigned char* __restrict__ yc8) {
    int idx = blockIdx.x * blockDim.x + threadIdx.x;
    int d0 = (idx & 511) * 8;
    int bt = idx >> 9;
    float y = ys[bt];
    ushort8v xcv = *(const ushort8v*)&xc[(long)bt * DINNER + d0];
    ushort8v rv = *(const ushort8v*)&xr[(long)bt * (2 * DINNER) + DINNER + d0];
    float val[8];
#pragma unroll
    for (int j = 0; j < 8; j++)
        val[j] = (y + dskip[d0 + j] * bf2f(xcv[j])) * siluf(bf2f(rv[j]));
    *(int2*)&yc8[(long)bt * DINNER + d0] = pack_fp8x8(val, 16.f);
}

extern "C" void kernel_launch(void* const* d_in, const int* in_sizes, int n_in,
                              void* d_out, int out_size, void* d_ws, size_t ws_size,
                              hipStream_t stream) {
    const float* x      = (const float*)d_in[0];
    const float* ln_g   = (const float*)d_in[1];
    const float* ln_b   = (const float*)d_in[2];
    const float* W_in   = (const float*)d_in[3];
    const float* conv_w = (const float*)d_in[4];
    const float* conv_b = (const float*)d_in[5];
    const float* W_xp   = (const float*)d_in[6];
    const float* W_dt   = (const float*)d_in[7];
    const float* b_dt   = (const float*)d_in[8];
    const float* A_log  = (const float*)d_in[9];
    const float* D_skip = (const float*)d_in[10];
    const float* W_out  = (const float*)d_in[11];
    float* out = (float*)d_out;

    // workspace carve
    char* ws = (char*)d_ws;
    const size_t nWin  = (size_t)2 * DINNER * DMODEL;
    const size_t nWdt  = (size_t)DINNER * DINNER;
    const size_t nWxp  = (size_t)2 * DSTATE * DINNER;
    const size_t nWout = (size_t)DMODEL * DINNER;

    unsigned char* wb_in8  = (unsigned char*)ws; ws += nWin;
    unsigned char* wb_dt8  = (unsigned char*)ws; ws += nWdt;
    unsigned char* wb_xp8  = (unsigned char*)ws; ws += nWxp;
    unsigned char* wb_out8 = (unsigned char*)ws; ws += nWout;
    unsigned char* xn8 = (unsigned char*)ws; ws += (size_t)NTOK * DMODEL;
    unsigned short* xr = (unsigned short*)ws; ws += (size_t)NTOK * 2 * DINNER * 2;
    unsigned short* xc = (unsigned short*)ws; ws += (size_t)NTOK * DINNER * 2;
    unsigned char*  xc8 = (unsigned char*)ws; ws += (size_t)NTOK * DINNER;
    unsigned char*  yc8 = (unsigned char*)ws; ws += (size_t)NTOK * DINNER;
    float* bc    = (float*)ws; ws += (size_t)NTOK * 2 * DSTATE * 4;
    float* bcp   = (float*)ws; ws += (size_t)NKSPLIT_XP * NTOK * 2 * DSTATE * 4;
    float* dmean = (float*)ws; ws += (size_t)NTOK * 4;
    float* ysb   = (float*)ws; ws += (size_t)NTOK * 4;
    float* h0    = (float*)ws; ws += (size_t)NTOK * DMODEL * 4;
    float* h1    = (float*)ws; ws += (size_t)NTOK * DMODEL * 4;
    float* p0    = (float*)ws; ws += (size_t)NTOK * DMODEL * 4;
    float* p1    = (float*)ws; ws += (size_t)NTOK * DMODEL * 4;

    const float* hprev = x;
    for (int lay = 0; lay < NLAYERS; lay++) {
        // 0+1) merged: LN(+residual) -> xn8  |  all-weight fp8 convert + dmean zero
        float* hcur = (lay & 1) ? h1 : h0;
        cvtln_kernel<<<NTOK + NCVT, 256, 0, stream>>>(
            W_in + (size_t)lay * nWin, W_dt + (size_t)lay * nWdt,
            W_xp + (size_t)lay * nWxp, W_out + (size_t)lay * nWout,
            wb_in8, wb_dt8, wb_xp8, wb_out8, dmean,
            p0, p1, hprev, ln_g + lay * DMODEL, ln_b + lay * DMODEL,
            lay > 0 ? 1 : 0, hcur, xn8);
        if (lay > 0) hprev = hcur;

        // 2) x_and_res = xn @ W_in^T  [4096 x 8192], K=2048B fp8: grid 16y x 32x = 512
        gemm8<0><<<512, 512, 0, stream>>>(xn8, wb_in8, nullptr, DMODEL, 32, 2 * DINNER,
                                          xr, nullptr, nullptr, nullptr, nullptr, 1.f / 256.f);

        // 3) causal depthwise conv + silu, 4 tokens/thread: grid 2048
        conv_silu4_kernel<<<NTOK / 4 * 512 / 256, 256, 0, stream>>>(
            xr, conv_w + (size_t)lay * DINNER * DCONV, conv_b + (size_t)lay * DINNER, xc, xc8);

        // 4) merged dt (blocks 0-255, full-K softplus) + xp (blocks 256-511, K-split x16)
        gemm8<4><<<512, 512, 0, stream>>>(xc8, wb_dt8, wb_xp8, DINNER, 64, 0,
                                          nullptr, bcp, nullptr,
                                          b_dt + (size_t)lay * DINNER, dmean, 1.f / 256.f);

        // 4c) bc = sum of partials
        bcsum_kernel<<<(NTOK * 256 / 4) / 256, 256, 0, stream>>>(bcp, bc);

        // 5) sequential scan -> ys (deep-prefetch)
        scan_kernel<<<BB, 64, 0, stream>>>(dmean, bc, A_log + (size_t)lay * DSTATE, ysb);

        // 6) y = (ys + D_skip*xc) * silu(res) -> fp8(x16)
        ycomb_kernel<<<NTOK * 512 / 256, 256, 0, stream>>>(
            ysb, xc, xr, D_skip + (size_t)lay * DINNER, yc8);

        // 7) W_out partials [4096 x 2048], K-split x2 (KT=32): grid 16y x 8x x 2k = 256
        gemm8<3><<<256, 512, 0, stream>>>(yc8, wb_out8, nullptr, DINNER, 32, DMODEL,
                                          nullptr, p0, p1, nullptr, nullptr, 1.f / 1024.f);
    }

    // final: out = p0 + p1 + h5
    combine3_kernel<<<(NTOK * DMODEL / 4) / 256, 256, 0, stream>>>(p0, p1, hprev, out);

    (void)in_sizes; (void)n_in; (void)out_size; (void)ws_size;
}

// Round 18
// 2916.678 us; speedup vs baseline: 1.3569x; 1.0670x over previous
//
#include <hip/hip_runtime.h>
#include <hip/hip_bf16.h>

#define NLAYERS 6
#define BB 8
#define TT 512
#define DMODEL 2048
#define DSTATE 128
#define DCONV 4
#define DINNER 4096
#define NTOK (BB*TT)              // 4096 tokens
#define NKSPLIT_XP 8
#define NCVT 20992                // (nWin+nWdt+nWxp+nWout)/2048

typedef __bf16 bf16x8 __attribute__((ext_vector_type(8)));
typedef float floatx4 __attribute__((ext_vector_type(4)));
typedef unsigned short ushort8v __attribute__((ext_vector_type(8)));
typedef unsigned short ushort4v __attribute__((ext_vector_type(4)));

__device__ __forceinline__ float bf2f(unsigned short u) {
    return __uint_as_float(((unsigned)u) << 16);
}
__device__ __forceinline__ unsigned short f2bf(float f) {
    unsigned u = __float_as_uint(f);
    unsigned r = u + 0x7FFFu + ((u >> 16) & 1u);   // round-nearest-even
    return (unsigned short)(r >> 16);
}
__device__ __forceinline__ float siluf(float x) { return x / (1.f + __expf(-x)); }
__device__ __forceinline__ float softplusf(float x) {
    return fmaxf(x, 0.f) + log1pf(__expf(-fabsf(x)));
}

__device__ __forceinline__ void gload16(const void* g, void* l) {
    __builtin_amdgcn_global_load_lds(
        (const __attribute__((address_space(1))) void*)g,
        (__attribute__((address_space(3))) void*)l, 16, 0, 0);
}

__device__ __forceinline__ int2 pack_fp8x8(const float* v, float scale) {
    int lo = __builtin_amdgcn_cvt_pk_fp8_f32(v[0] * scale, v[1] * scale, 0, false);
    lo = __builtin_amdgcn_cvt_pk_fp8_f32(v[2] * scale, v[3] * scale, lo, true);
    int hi = __builtin_amdgcn_cvt_pk_fp8_f32(v[4] * scale, v[5] * scale, 0, false);
    hi = __builtin_amdgcn_cvt_pk_fp8_f32(v[6] * scale, v[7] * scale, hi, true);
    int2 o = {lo, hi};
    return o;
}

// byte-select of cvt_f32_fp8 must be a LITERAL constant -> hard-coded 4-call helper
__device__ __forceinline__ void unpack_fp8x4(int wrd, float* o) {
    o[0] = __builtin_amdgcn_cvt_f32_fp8(wrd, 0);
    o[1] = __builtin_amdgcn_cvt_f32_fp8(wrd, 1);
    o[2] = __builtin_amdgcn_cvt_f32_fp8(wrd, 2);
    o[3] = __builtin_amdgcn_cvt_f32_fp8(wrd, 3);
}

#define BARR __builtin_amdgcn_s_barrier()
#define SCHB __builtin_amdgcn_sched_barrier(0)
#define PRIO1 __builtin_amdgcn_s_setprio(1)
#define PRIO0 __builtin_amdgcn_s_setprio(0)

// ======= merged [LayerNorm(+residual) -> xn fp8] + [all-weight fp32->fp8 cvt + dmean zero] =======
__global__ __launch_bounds__(256) void cvtln_kernel(const float* __restrict__ Win,
                                                    const float* __restrict__ Wdt,
                                                    const float* __restrict__ Wxp,
                                                    const float* __restrict__ Wout,
                                                    unsigned char* __restrict__ dIn,
                                                    unsigned char* __restrict__ dDt,
                                                    unsigned char* __restrict__ dXp,
                                                    unsigned char* __restrict__ dOut,
                                                    float* __restrict__ dmean,
                                                    const float* __restrict__ p0,
                                                    const float* __restrict__ p1,
                                                    const float* __restrict__ hin,
                                                    const float* __restrict__ g,
                                                    const float* __restrict__ b,
                                                    int hasP,
                                                    float* __restrict__ hout,
                                                    unsigned char* __restrict__ out8) {
    if (blockIdx.x < NTOK) {
        const int row = blockIdx.x;
        const long rb = (long)row * DMODEL;
        const int base = threadIdx.x * 8;
        float vv[8];
        float4 v0 = *(const float4*)(hin + rb + base);
        float4 v1 = *(const float4*)(hin + rb + base + 4);
        vv[0]=v0.x; vv[1]=v0.y; vv[2]=v0.z; vv[3]=v0.w;
        vv[4]=v1.x; vv[5]=v1.y; vv[6]=v1.z; vv[7]=v1.w;
        if (hasP) {
            float4 a0 = *(const float4*)(p0 + rb + base);
            float4 a1 = *(const float4*)(p0 + rb + base + 4);
            float4 c0 = *(const float4*)(p1 + rb + base);
            float4 c1 = *(const float4*)(p1 + rb + base + 4);
            vv[0]+=a0.x+c0.x; vv[1]+=a0.y+c0.y; vv[2]+=a0.z+c0.z; vv[3]+=a0.w+c0.w;
            vv[4]+=a1.x+c1.x; vv[5]+=a1.y+c1.y; vv[6]+=a1.z+c1.z; vv[7]+=a1.w+c1.w;
            float4 w0 = {vv[0],vv[1],vv[2],vv[3]}, w1 = {vv[4],vv[5],vv[6],vv[7]};
            *(float4*)(hout + rb + base) = w0;
            *(float4*)(hout + rb + base + 4) = w1;
        }
        float s = 0.f, s2 = 0.f;
#pragma unroll
        for (int j = 0; j < 8; j++) { s += vv[j]; s2 += vv[j] * vv[j]; }
#pragma unroll
        for (int off = 32; off >= 1; off >>= 1) {
            s += __shfl_xor(s, off);
            s2 += __shfl_xor(s2, off);
        }
        __shared__ float red[8];
        int wave = threadIdx.x >> 6, lane = threadIdx.x & 63;
        if (lane == 0) { red[wave] = s; red[4 + wave] = s2; }
        __syncthreads();
        s = red[0] + red[1] + red[2] + red[3];
        s2 = red[4] + red[5] + red[6] + red[7];
        float mu = s * (1.f / DMODEL);
        float var = s2 * (1.f / DMODEL) - mu * mu;
        float rs = rsqrtf(var + 1e-5f);
        float nv[8];
#pragma unroll
        for (int j = 0; j < 8; j++)
            nv[j] = (vv[j] - mu) * rs * g[base + j] + b[base + j];
        *(int2*)&out8[rb + base] = pack_fp8x8(nv, 4.f);
    } else {
        const long nWin  = (long)2 * DINNER * DMODEL;
        const long nWdt  = (long)DINNER * DINNER;
        const long nWxp  = (long)2 * DSTATE * DINNER;
        const long cum1 = nWin, cum2 = cum1 + nWdt, cum3 = cum2 + nWxp;
        const int cb = blockIdx.x - NTOK;
        long i = (long)cb * 2048 + threadIdx.x * 8;
        const float* s; unsigned char* d; long off;
        if (i < cum1)      { s = Win;  d = dIn;  off = i; }
        else if (i < cum2) { s = Wdt;  d = dDt;  off = i - cum1; }
        else if (i < cum3) { s = Wxp;  d = dXp;  off = i - cum2; }
        else               { s = Wout; d = dOut; off = i - cum3; }
        float v[8];
        float4 v0 = *(const float4*)(s + off);
        float4 v1 = *(const float4*)(s + off + 4);
        v[0]=v0.x; v[1]=v0.y; v[2]=v0.z; v[3]=v0.w;
        v[4]=v1.x; v[5]=v1.y; v[6]=v1.z; v[7]=v1.w;
        *(int2*)(d + off) = pack_fp8x8(v, 64.f);
        if (cb < 8) {
            float2 z = {0.f, 0.f};
            *(float2*)&dmean[(cb * 256 + threadIdx.x) * 2] = z;
        }
    }
}

// ---------------- final combine: out = p0 + p1 + h ----------------
__global__ __launch_bounds__(256) void combine3_kernel(const float* __restrict__ p0,
                                                       const float* __restrict__ p1,
                                                       const float* __restrict__ h,
                                                       float* __restrict__ out) {
    long i = (long)(blockIdx.x * blockDim.x + threadIdx.x) * 4;
    float4 a = *(const float4*)(p0 + i);
    float4 b = *(const float4*)(p1 + i);
    float4 c = *(const float4*)(h + i);
    float4 o = {a.x+b.x+c.x, a.y+b.y+c.y, a.z+b.z+c.z, a.w+b.w+c.w};
    *(float4*)(out + i) = o;
}

// ========== A/B: 128x256 fp8 W_in GEMM, 256 thr, 3x24KB LDS -> 2 blocks/CU ==========
// 4 waves: wm=w>>1 (M 64-band), wn=w&1 (N 128-band); acc[4][8].
// Per tile: vmcnt(6) [tile t landed, t+1 in flight]; barrier; STAGE(t+2, 6 gload16);
// 24 ds_read_b64; lgkm(12) -> 32 MFMA k0; lgkm(0) -> 32 MFMA k1. Same verified swizzle
// family. Epilogue: cols<DINNER -> xrp bf16; cols>=DINNER -> res8 fp8(x16).
__global__ __launch_bounds__(256, 2) void gemm_in2b(const unsigned char* __restrict__ A8,
                                                    const unsigned char* __restrict__ B8,
                                                    unsigned short* __restrict__ xrp,
                                                    unsigned char* __restrict__ res8) {
    __shared__ __align__(16) char lds[3 * 24576];
    const int tid = threadIdx.x;
    const int w = tid >> 6, lane = tid & 63;
    const int wm = w >> 1, wn = w & 1;

    const int xcd = blockIdx.x & 7;
    const int l = blockIdx.x >> 3;
    const int by = xcd * 4 + (l & 3);    // 0..31
    const int bx = l >> 2;               // 0..31
    const long rowBase = (long)by * 128;
    const long colBase = (long)bx * 256;

    int cbs[2];
#pragma unroll
    for (int s = 0; s < 2; s++)
        cbs[s] = (((((lane & 1) << 2) | (s * 2 + (lane >> 5))) ^ ((lane >> 1) & 7)) * 16)
                 + ((lane >> 4) & 1) * 8;
    const char* rdA = lds + wm * 4096 + ((lane >> 1) & 7) * 128;
    const char* rdB = lds + 8192 + wn * 8192 + ((lane >> 1) & 7) * 128;

    const int t8 = tid >> 3;
    const int ch3 = (tid & 7) ^ (t8 & 7);
    const int srow = 2 * t8 + (ch3 >> 2);
    const int coff = (ch3 & 3) * 16;
    const size_t Kb = (size_t)DMODEL;    // K bytes (fp8)
    const char* pA1 = (const char*)A8 + (rowBase + srow) * Kb + coff;
    const char* pA2 = (const char*)A8 + (rowBase + 64 + srow) * Kb + coff;
    const char* pB1 = (const char*)B8 + (colBase + srow) * Kb + coff;
    const char* pB2 = (const char*)B8 + (colBase + 64 + srow) * Kb + coff;
    const char* pB3 = (const char*)B8 + (colBase + 128 + srow) * Kb + coff;
    const char* pB4 = (const char*)B8 + (colBase + 192 + srow) * Kb + coff;
    const long wb = (long)w * 1024;

    floatx4 acc[4][8];
#pragma unroll
    for (int m = 0; m < 4; m++)
#pragma unroll
        for (int n = 0; n < 8; n++) acc[m][n] = floatx4{0.f, 0.f, 0.f, 0.f};

#define STG2(BUF, OFF) do { \
    gload16(pA1 + (OFF), lds + (BUF)*24576 + wb); \
    gload16(pA2 + (OFF), lds + (BUF)*24576 + 4096 + wb); \
    gload16(pB1 + (OFF), lds + (BUF)*24576 + 8192 + wb); \
    gload16(pB2 + (OFF), lds + (BUF)*24576 + 12288 + wb); \
    gload16(pB3 + (OFF), lds + (BUF)*24576 + 16384 + wb); \
    gload16(pB4 + (OFF), lds + (BUF)*24576 + 20480 + wb); } while(0)

    const int KT = DMODEL / 64;    // 32 tiles
    STG2(0, 0);
    STG2(1, 64);

    for (int t = 0; t < KT; t++) {
        const long bo = (long)(t % 3) * 24576;
        const int bufS = (t + 2) % 3;
        const size_t off2 = (size_t)((t + 2 < KT) ? (t + 2) : (KT - 1)) * 64;
        asm volatile("s_waitcnt vmcnt(6)");
        BARR;
        STG2(bufS, off2);
        long b0[8], a0[4], b1[8], a1[4];
#pragma unroll
        for (int n = 0; n < 8; n++) b0[n] = *(const long*)(rdB + bo + n * 1024 + cbs[0]);
#pragma unroll
        for (int m = 0; m < 4; m++) a0[m] = *(const long*)(rdA + bo + m * 1024 + cbs[0]);
#pragma unroll
        for (int n = 0; n < 8; n++) b1[n] = *(const long*)(rdB + bo + n * 1024 + cbs[1]);
#pragma unroll
        for (int m = 0; m < 4; m++) a1[m] = *(const long*)(rdA + bo + m * 1024 + cbs[1]);
        asm volatile("s_waitcnt lgkmcnt(12)"); SCHB;
        PRIO1;
#pragma unroll
        for (int m = 0; m < 4; m++)
#pragma unroll
            for (int n = 0; n < 8; n++)
                acc[m][n] = __builtin_amdgcn_mfma_f32_16x16x32_fp8_fp8(b0[n], a0[m], acc[m][n], 0, 0, 0);
        PRIO0;
        asm volatile("s_waitcnt lgkmcnt(0)"); SCHB;
        PRIO1;
#pragma unroll
        for (int m = 0; m < 4; m++)
#pragma unroll
            for (int n = 0; n < 8; n++)
                acc[m][n] = __builtin_amdgcn_mfma_f32_16x16x32_fp8_fp8(b1[n], a1[m], acc[m][n], 0, 0, 0);
        PRIO0;
    }
#undef STG2

    // epilogue (M-row = lane&15, N-col = (lane>>4)*4 + reg); SC = 1/256
    const int lrow = lane & 15, cg = (lane >> 4) * 4;
    const float SC = 1.f / 256.f;
    if (colBase < DINNER) {
#pragma unroll
        for (int mi = 0; mi < 4; mi++)
#pragma unroll
            for (int n = 0; n < 8; n++) {
                long row = rowBase + wm * 64 + mi * 16 + lrow;
                long col = colBase + wn * 128 + n * 16 + cg;
                ushort4v o = {f2bf(acc[mi][n][0] * SC), f2bf(acc[mi][n][1] * SC),
                              f2bf(acc[mi][n][2] * SC), f2bf(acc[mi][n][3] * SC)};
                *(ushort4v*)&xrp[row * DINNER + col] = o;
            }
    } else {
#pragma unroll
        for (int mi = 0; mi < 4; mi++)
#pragma unroll
            for (int n = 0; n < 8; n++) {
                long row = rowBase + wm * 64 + mi * 16 + lrow;
                long col = colBase - DINNER + wn * 128 + n * 16 + cg;
                int pw = __builtin_amdgcn_cvt_pk_fp8_f32(acc[mi][n][0] * SC * 16.f,
                                                         acc[mi][n][1] * SC * 16.f, 0, false);
                pw = __builtin_amdgcn_cvt_pk_fp8_f32(acc[mi][n][2] * SC * 16.f,
                                                     acc[mi][n][3] * SC * 16.f, pw, true);
                *(int*)&res8[row * DINNER + col] = pw;
            }
    }
}

// ============ 256x256 fp8 GEMM, BK=64 bytes, 5-buffer LDS, depth 4 (verified) ============
// EPI: 3 = fp32 K-part *SC (W_out); 4 = merged dt+xp.
template <int EPI>
__global__ __launch_bounds__(512, 1) void gemm8(const unsigned char* __restrict__ A8,
                                                const unsigned char* __restrict__ B8,
                                                const unsigned char* __restrict__ Bx8,
                                                int KstrB, int KT, int ldc,
                                                float* __restrict__ of0,
                                                float* __restrict__ of1,
                                                const float* __restrict__ bias,
                                                float* __restrict__ dmean,
                                                float SC) {
    __shared__ __align__(16) char lds[5 * 32768];
    const int tid = threadIdx.x;
    const int w = tid >> 6, lane = tid & 63;
    const int wm = w >> 2, wn = w & 3;

    int by, bx = 0, kpart = 0, KTloc = KT;
    bool isXp = false;
    const unsigned char* Bsel = B8;
    if constexpr (EPI == 4) {
        isXp = blockIdx.x >= 256;
        const int b2 = isXp ? (blockIdx.x - 256) : blockIdx.x;
        const int xcd = b2 & 7;
        const int l = b2 >> 3;
        by = xcd * 2 + (l & 1);
        const int rest = l >> 1;
        if (isXp) { kpart = rest; KTloc = 8; Bsel = Bx8; }
        else { bx = rest; KTloc = 64; }
    } else {
        const int xcd = blockIdx.x & 7;
        const int l = blockIdx.x >> 3;
        by = xcd * 2 + (l & 1);
        const int rest = l >> 1;
        bx = rest & 7; kpart = rest >> 3;
    }
    const long rowBase = (long)by * 256;
    const long colBase = (long)bx * 256;
    const long K0b = (long)kpart * KTloc * 64;

    int cbs[2];
#pragma unroll
    for (int s = 0; s < 2; s++)
        cbs[s] = (((((lane & 1) << 2) | (s * 2 + (lane >> 5))) ^ ((lane >> 1) & 7)) * 16)
                 + ((lane >> 4) & 1) * 8;
    const char* rdA = lds + wm * 8192 + ((lane >> 1) & 7) * 128;
    const char* rdB = lds + 16384 + wn * 4096 + ((lane >> 1) & 7) * 128;

    const int t8 = tid >> 3;
    const int ch3 = (tid & 7) ^ (t8 & 7);
    const int srow = 2 * t8 + (ch3 >> 2);
    const int coff = (ch3 & 3) * 16;
    const size_t Kb = (size_t)KstrB;
    const char* pA1 = (const char*)A8 + (rowBase + srow) * Kb + coff + K0b;
    const char* pA2 = (const char*)A8 + (rowBase + 128 + srow) * Kb + coff + K0b;
    const char* pB1 = (const char*)Bsel + (colBase + srow) * Kb + coff + K0b;
    const char* pB2 = (const char*)Bsel + (colBase + 128 + srow) * Kb + coff + K0b;
    const long wb = (long)w * 1024;

    floatx4 acc[8][4];
#pragma unroll
    for (int m = 0; m < 8; m++)
#pragma unroll
        for (int n = 0; n < 4; n++) acc[m][n] = floatx4{0.f, 0.f, 0.f, 0.f};

#define STG8(BUF, OFF) do { \
    gload16(pA1 + (OFF), lds + (BUF)*32768 + wb); \
    gload16(pA2 + (OFF), lds + (BUF)*32768 + 8192 + wb); \
    gload16(pB1 + (OFF), lds + (BUF)*32768 + 16384 + wb); \
    gload16(pB2 + (OFF), lds + (BUF)*32768 + 24576 + wb); } while(0)

    STG8(0, 0);
    STG8(1, (size_t)((1 < KTloc) ? 1 : KTloc - 1) * 64);
    STG8(2, (size_t)((2 < KTloc) ? 2 : KTloc - 1) * 64);
    STG8(3, (size_t)((3 < KTloc) ? 3 : KTloc - 1) * 64);

    for (int t = 0; t < KTloc; t++) {
        const long bo = (long)(t % 5) * 32768;
        const int bufS = (t + 4) % 5;
        const size_t off4 = (size_t)((t + 4 < KTloc) ? (t + 4) : (KTloc - 1)) * 64;
        asm volatile("s_waitcnt vmcnt(12)");
        BARR;
        STG8(bufS, off4);
        long b0[4], a0[8], b1[4], a1[8];
#pragma unroll
        for (int n = 0; n < 4; n++) b0[n] = *(const long*)(rdB + bo + n * 1024 + cbs[0]);
#pragma unroll
        for (int m = 0; m < 8; m++) a0[m] = *(const long*)(rdA + bo + m * 1024 + cbs[0]);
#pragma unroll
        for (int n = 0; n < 4; n++) b1[n] = *(const long*)(rdB + bo + n * 1024 + cbs[1]);
#pragma unroll
        for (int m = 0; m < 8; m++) a1[m] = *(const long*)(rdA + bo + m * 1024 + cbs[1]);
        asm volatile("s_waitcnt lgkmcnt(12)"); SCHB;
        PRIO1;
#pragma unroll
        for (int m = 0; m < 8; m++)
#pragma unroll
            for (int n = 0; n < 4; n++)
                acc[m][n] = __builtin_amdgcn_mfma_f32_16x16x32_fp8_fp8(b0[n], a0[m], acc[m][n], 0, 0, 0);
        PRIO0;
        asm volatile("s_waitcnt lgkmcnt(0)"); SCHB;
        PRIO1;
#pragma unroll
        for (int m = 0; m < 8; m++)
#pragma unroll
            for (int n = 0; n < 4; n++)
                acc[m][n] = __builtin_amdgcn_mfma_f32_16x16x32_fp8_fp8(b1[n], a1[m], acc[m][n], 0, 0, 0);
        PRIO0;
    }
#undef STG8

    const int lrow = lane & 15, cg = (lane >> 4) * 4;
    if constexpr (EPI == 3) {
        float* op = (kpart == 0) ? of0 : of1;
#pragma unroll
        for (int mi = 0; mi < 8; mi++)
#pragma unroll
            for (int n = 0; n < 4; n++) {
                long row = rowBase + wm * 128 + mi * 16 + lrow;
                long col = colBase + wn * 64 + n * 16 + cg;
                *(floatx4*)&op[row * ldc + col] = acc[mi][n] * SC;
            }
    } else {   // EPI == 4
        if (!isXp) {
            float4 bi[4];
#pragma unroll
            for (int n = 0; n < 4; n++)
                bi[n] = *(const float4*)&bias[colBase + wn * 64 + n * 16 + cg];
#pragma unroll
            for (int mi = 0; mi < 8; mi++) {
                float s = 0.f;
#pragma unroll
                for (int n = 0; n < 4; n++) {
                    s += softplusf(acc[mi][n][0] * SC + bi[n].x);
                    s += softplusf(acc[mi][n][1] * SC + bi[n].y);
                    s += softplusf(acc[mi][n][2] * SC + bi[n].z);
                    s += softplusf(acc[mi][n][3] * SC + bi[n].w);
                }
                s += __shfl_xor(s, 16);
                s += __shfl_xor(s, 32);
                if ((lane >> 4) == 0)
                    atomicAdd(&dmean[rowBase + wm * 128 + mi * 16 + lrow], s);
            }
        } else {
            float* op = of0 + (long)kpart * NTOK * 256;
#pragma unroll
            for (int mi = 0; mi < 8; mi++)
#pragma unroll
                for (int n = 0; n < 4; n++) {
                    long row = rowBase + wm * 128 + mi * 16 + lrow;
                    long col = wn * 64 + n * 16 + cg;
                    *(floatx4*)&op[row * 256 + col] = acc[mi][n] * SC;
                }
        }
    }
}

// -------- causal depthwise conv1d + bias + silu, 4 tokens/thread; writes xc8 only --------
__global__ __launch_bounds__(256) void conv_silu4_kernel(const unsigned short* __restrict__ xrp,
                                                         const float* __restrict__ w,
                                                         const float* __restrict__ cb,
                                                         unsigned char* __restrict__ xc8) {
    int idx = blockIdx.x * 256 + threadIdx.x;   // (NTOK/4) * 512 threads
    int d0 = (idx & 511) * 8;
    int g = idx >> 9;
    int bt0 = g * 4;
    int t0 = bt0 & (TT - 1);
    float rows[7][8];
#pragma unroll
    for (int j = 0; j < 7; j++) {
        if (t0 - 3 + j < 0) {
#pragma unroll
            for (int e = 0; e < 8; e++) rows[j][e] = 0.f;
        } else {
            ushort8v v = *(const ushort8v*)&xrp[(long)(bt0 - 3 + j) * DINNER + d0];
#pragma unroll
            for (int e = 0; e < 8; e++) rows[j][e] = bf2f(v[e]);
        }
    }
    float4 wv[8];
#pragma unroll
    for (int e = 0; e < 8; e++) wv[e] = *(const float4*)&w[(d0 + e) * DCONV];
    float cbv[8];
#pragma unroll
    for (int e = 0; e < 8; e++) cbv[e] = cb[d0 + e];
#pragma unroll
    for (int tj = 0; tj < 4; tj++) {
        float sv[8];
#pragma unroll
        for (int e = 0; e < 8; e++) {
            float a = cbv[e];
            a += rows[tj][e] * wv[e].x;
            a += rows[tj + 1][e] * wv[e].y;
            a += rows[tj + 2][e] * wv[e].z;
            a += rows[tj + 3][e] * wv[e].w;
            sv[e] = siluf(a);
        }
        *(int2*)&xc8[(long)(bt0 + tj) * DINNER + d0] = pack_fp8x8(sv, 4.f);
    }
}

// ---------------- bc = sum of 8 K-split partials ----------------
__global__ __launch_bounds__(256) void bcsum_kernel(const float* __restrict__ bcp,
                                                    float* __restrict__ bc) {
    long i = (long)(blockIdx.x * blockDim.x + threadIdx.x) * 4;
    const long S = (long)NTOK * 256;
    float4 o = *(const float4*)(bcp + i);
#pragma unroll
    for (int p = 1; p < NKSPLIT_XP; p++) {
        float4 v = *(const float4*)(bcp + (long)p * S + i);
        o.x += v.x; o.y += v.y; o.z += v.z; o.w += v.w;
    }
    *(float4*)(bc + i) = o;
}

// -------- sequential selective-scan, double-buffered 4-step batches (deep prefetch) --------
__global__ void scan_kernel(const float* __restrict__ dmean, const float* __restrict__ bcmat,
                            const float* __restrict__ A_log, float* __restrict__ ys) {
    int b = blockIdx.x, lane = threadIdx.x;
    float A0 = -expf(A_log[lane]);
    float A1 = -expf(A_log[lane + 64]);
    float h0 = 0.f, h1 = 0.f;
    const float inv = 1.f / (float)DINNER;
    const float* rowp = bcmat + (long)b * TT * (2 * DSTATE);
    const float* dmp = dmean + b * TT;

    float cB0[4], cB1[4], cC0[4], cC1[4]; float4 cDM;
    float nB0[4], nB1[4], nC0[4], nC1[4]; float4 nDM;

#define LOADB(B0_, B1_, C0_, C1_, DM_, T0) do { \
    int tt_ = (T0); if (tt_ > TT - 4) tt_ = TT - 4; \
    _Pragma("unroll") for (int j_ = 0; j_ < 4; j_++) { \
        const float* rp_ = rowp + (long)(tt_ + j_) * 256; \
        B0_[j_] = rp_[lane]; B1_[j_] = rp_[64 + lane]; \
        C0_[j_] = rp_[128 + lane]; C1_[j_] = rp_[192 + lane]; } \
    DM_ = *(const float4*)&dmp[tt_]; } while (0)

#define COMPUTE4(B0_, B1_, C0_, C1_, DM_, T0) do { \
    float vv_[4]; \
    const float dms_[4] = {DM_.x, DM_.y, DM_.z, DM_.w}; \
    _Pragma("unroll") for (int j_ = 0; j_ < 4; j_++) { \
        float dm_ = dms_[j_] * inv; \
        h0 = h0 * __expf(dm_ * A0) + B0_[j_]; \
        h1 = h1 * __expf(dm_ * A1) + B1_[j_]; \
        vv_[j_] = h0 * C0_[j_] + h1 * C1_[j_]; } \
    _Pragma("unroll") for (int off_ = 32; off_ >= 1; off_ >>= 1) { \
        vv_[0] += __shfl_xor(vv_[0], off_); vv_[1] += __shfl_xor(vv_[1], off_); \
        vv_[2] += __shfl_xor(vv_[2], off_); vv_[3] += __shfl_xor(vv_[3], off_); } \
    if (lane == 0) { \
        float4 o_ = {vv_[0], vv_[1], vv_[2], vv_[3]}; \
        *(float4*)&ys[b * TT + (T0)] = o_; } } while (0)

    LOADB(cB0, cB1, cC0, cC1, cDM, 0);
    LOADB(nB0, nB1, nC0, nC1, nDM, 4);

    for (int t0 = 0; t0 < TT; t0 += 8) {
        COMPUTE4(cB0, cB1, cC0, cC1, cDM, t0);
        LOADB(cB0, cB1, cC0, cC1, cDM, t0 + 8);
        COMPUTE4(nB0, nB1, nC0, nC1, nDM, t0 + 4);
        LOADB(nB0, nB1, nC0, nC1, nDM, t0 + 12);
    }
#undef LOADB
#undef COMPUTE4
}

// ------- y = (ys + D_skip*xc8/4) * silu(res8/16) -> fp8(x16) -------
__global__ __launch_bounds__(256) void ycomb_kernel(const float* __restrict__ ys,
                                                    const unsigned char* __restrict__ xc8,
                                                    const unsigned char* __restrict__ res8,
                                                    const float* __restrict__ dskip,
                                                    unsigned char* __restrict__ yc8) {
    int idx = blockIdx.x * blockDim.x + threadIdx.x;
    int d0 = (idx & 511) * 8;
    int bt = idx >> 9;
    float y = ys[bt];
    int2 xv = *(const int2*)&xc8[(long)bt * DINNER + d0];
    int2 rv = *(const int2*)&res8[(long)bt * DINNER + d0];
    float xf[8], rf[8];
    unpack_fp8x4(xv.x, xf);
    unpack_fp8x4(xv.y, xf + 4);
    unpack_fp8x4(rv.x, rf);
    unpack_fp8x4(rv.y, rf + 4);
    float val[8];
#pragma unroll
    for (int j = 0; j < 8; j++)
        val[j] = (y + dskip[d0 + j] * (xf[j] * 0.25f)) * siluf(rf[j] * 0.0625f);
    *(int2*)&yc8[(long)bt * DINNER + d0] = pack_fp8x8(val, 16.f);
}

extern "C" void kernel_launch(void* const* d_in, const int* in_sizes, int n_in,
                              void* d_out, int out_size, void* d_ws, size_t ws_size,
                              hipStream_t stream) {
    const float* x      = (const float*)d_in[0];
    const float* ln_g   = (const float*)d_in[1];
    const float* ln_b   = (const float*)d_in[2];
    const float* W_in   = (const float*)d_in[3];
    const float* conv_w = (const float*)d_in[4];
    const float* conv_b = (const float*)d_in[5];
    const float* W_xp   = (const float*)d_in[6];
    const float* W_dt   = (const float*)d_in[7];
    const float* b_dt   = (const float*)d_in[8];
    const float* A_log  = (const float*)d_in[9];
    const float* D_skip = (const float*)d_in[10];
    const float* W_out  = (const float*)d_in[11];
    float* out = (float*)d_out;

    // workspace carve
    char* ws = (char*)d_ws;
    const size_t nWin  = (size_t)2 * DINNER * DMODEL;
    const size_t nWdt  = (size_t)DINNER * DINNER;
    const size_t nWxp  = (size_t)2 * DSTATE * DINNER;
    const size_t nWout = (size_t)DMODEL * DINNER;

    unsigned char* wb_in8  = (unsigned char*)ws; ws += nWin;
    unsigned char* wb_dt8  = (unsigned char*)ws; ws += nWdt;
    unsigned char* wb_xp8  = (unsigned char*)ws; ws += nWxp;
    unsigned char* wb_out8 = (unsigned char*)ws; ws += nWout;
    unsigned char* xn8 = (unsigned char*)ws; ws += (size_t)NTOK * DMODEL;
    unsigned short* xrp = (unsigned short*)ws; ws += (size_t)NTOK * DINNER * 2;
    unsigned char*  res8 = (unsigned char*)ws; ws += (size_t)NTOK * DINNER;
    unsigned char*  xc8 = (unsigned char*)ws; ws += (size_t)NTOK * DINNER;
    unsigned char*  yc8 = (unsigned char*)ws; ws += (size_t)NTOK * DINNER;
    float* bc    = (float*)ws; ws += (size_t)NTOK * 2 * DSTATE * 4;
    float* bcp   = (float*)ws; ws += (size_t)NKSPLIT_XP * NTOK * 2 * DSTATE * 4;
    float* dmean = (float*)ws; ws += (size_t)NTOK * 4;
    float* ysb   = (float*)ws; ws += (size_t)NTOK * 4;
    float* h0    = (float*)ws; ws += (size_t)NTOK * DMODEL * 4;
    float* h1    = (float*)ws; ws += (size_t)NTOK * DMODEL * 4;
    float* p0    = (float*)ws; ws += (size_t)NTOK * DMODEL * 4;
    float* p1    = (float*)ws; ws += (size_t)NTOK * DMODEL * 4;

    const float* hprev = x;
    for (int lay = 0; lay < NLAYERS; lay++) {
        // 0+1) merged: LN(+residual) -> xn8  |  all-weight fp8 convert + dmean zero
        float* hcur = (lay & 1) ? h1 : h0;
        cvtln_kernel<<<NTOK + NCVT, 256, 0, stream>>>(
            W_in + (size_t)lay * nWin, W_dt + (size_t)lay * nWdt,
            W_xp + (size_t)lay * nWxp, W_out + (size_t)lay * nWout,
            wb_in8, wb_dt8, wb_xp8, wb_out8, dmean,
            p0, p1, hprev, ln_g + lay * DMODEL, ln_b + lay * DMODEL,
            lay > 0 ? 1 : 0, hcur, xn8);
        if (lay > 0) hprev = hcur;

        // 2) W_in GEMM, 2-blocks/CU A/B geometry: grid 32y x 32x = 1024, 256 thr
        gemm_in2b<<<1024, 256, 0, stream>>>(xn8, wb_in8, xrp, res8);

        // 3) causal depthwise conv + silu -> xc8 only
        conv_silu4_kernel<<<NTOK / 4 * 512 / 256, 256, 0, stream>>>(
            xrp, conv_w + (size_t)lay * DINNER * DCONV, conv_b + (size_t)lay * DINNER, xc8);

        // 4) merged dt (blocks 0-255, full-K softplus) + xp (blocks 256-383, K-split x8)
        gemm8<4><<<384, 512, 0, stream>>>(xc8, wb_dt8, wb_xp8, DINNER, 64, 0,
                                          bcp, nullptr,
                                          b_dt + (size_t)lay * DINNER, dmean, 1.f / 256.f);

        // 4c) bc = sum of partials
        bcsum_kernel<<<(NTOK * 256 / 4) / 256, 256, 0, stream>>>(bcp, bc);

        // 5) sequential scan -> ys (deep-prefetch)
        scan_kernel<<<BB, 64, 0, stream>>>(dmean, bc, A_log + (size_t)lay * DSTATE, ysb);

        // 6) y = (ys + D_skip*xc) * silu(res) -> fp8(x16)
        ycomb_kernel<<<NTOK * 512 / 256, 256, 0, stream>>>(
            ysb, xc8, res8, D_skip + (size_t)lay * DINNER, yc8);

        // 7) W_out partials [4096 x 2048], K-split x2 (KT=32): grid 16y x 8x x 2k = 256
        gemm8<3><<<256, 512, 0, stream>>>(yc8, wb_out8, nullptr, DINNER, 32, DMODEL,
                                          p0, p1, nullptr, nullptr, 1.f / 1024.f);
    }

    // final: out = p0 + p1 + h5
    combine3_kernel<<<(NTOK * DMODEL / 4) / 256, 256, 0, stream>>>(p0, p1, hprev, out);

    (void)in_sizes; (void)n_in; (void)out_size; (void)ws_size;
}